// Round 9
// baseline (230.818 us; speedup 1.0000x reference)
//
#include <hip/hip_runtime.h>
#include <hip/hip_bf16.h>
#include <cstddef>

// Problem constants (SelfAttention: B=4, T=2048, H=16, Dh=64, C=1024)
#define B_  4
#define T_  2048
#define H_  16
#define DH  64
#define C_  1024
#define BH  64    // B_*H_

typedef float  f32x16 __attribute__((ext_vector_type(16)));
typedef __bf16 bf16x8 __attribute__((ext_vector_type(8)));
typedef __bf16 bf16x4 __attribute__((ext_vector_type(4)));

#define MFMA32(a, b, c) __builtin_amdgcn_mfma_f32_32x32x16_bf16(a, b, c, 0, 0, 0)

// mfma_f32_32x32x16_bf16 layouts (cdna4_isa / m74,m101 verified C/D):
//   A[m][k]: m = lane&31, k = (lane>>5)*8 + j   (8 bf16 per lane, b128)
//   B[k][n]: n = lane&31, k = (lane>>5)*8 + j
//   C/D:     col = lane&31, row = (reg&3) + 8*(reg>>2) + 4*(lane>>5)
//
// FRAGMENT-MAJOR global layouts (a fragment load = base + lane*16B -> one
// coalesced 1KB transaction per wave):
//   Kf[bh][kt64][rh][ks][lane][8]   (K rows,   QK^T A-operand)
//   Vf[bh][kt64][dh][c ][lane][8]   (V^T rows, PV A-operand)
//   Af[(bh*16)+qt][wv][ks][lane][8] (attn out, proj A-operand)
//   Wpf[eb][cb][n][ks][lane][8]     (Wp,      proj B-operand)

__device__ __forceinline__ unsigned cvt_pk_bf16(float lo, float hi) {
    unsigned r;
    asm("v_cvt_pk_bf16_f32 %0, %1, %2" : "=v"(r) : "v"(lo), "v"(hi));
    return r;
}

// ---------------------------------------------------------------------------
// Kernel 0: Wq/Wk/Wv fp32 -> bf16 pre-conversion (once; into dead af region).
// ---------------------------------------------------------------------------
__global__ __launch_bounds__(256) void wconv_kernel(
    const float* __restrict__ Wq, const float* __restrict__ Wk,
    const float* __restrict__ Wv, __bf16* __restrict__ wqkv)
{
    const int tid = blockIdx.x * 256 + threadIdx.x;   // 0..3071
    const float* srcs[3] = {Wq, Wk, Wv};
    const int mat = tid >> 10;                        // 1024 threads per matrix
    const int off = (tid & 1023) * 4;
    const float4 w4 = *(const float4*)(srcs[mat] + off);
    const unsigned lo = ((unsigned)__builtin_bit_cast(unsigned short, (__bf16)w4.y) << 16)
                      | (unsigned)__builtin_bit_cast(unsigned short, (__bf16)w4.x);
    const unsigned hi = ((unsigned)__builtin_bit_cast(unsigned short, (__bf16)w4.w) << 16)
                      | (unsigned)__builtin_bit_cast(unsigned short, (__bf16)w4.z);
    uint2 p; p.x = lo; p.y = hi;
    *(uint2*)(wqkv + mat * 4096 + off) = p;
}

// ---------------------------------------------------------------------------
// Kernel 1: QKV projection, bf16 MFMA (UNCHANGED from round 8).
// ---------------------------------------------------------------------------
__global__ __launch_bounds__(256) void qkv_kernel(
    const float* __restrict__ x,
    const __bf16* __restrict__ wqkv,
    const float* __restrict__ bq, const float* __restrict__ bk,
    const float* __restrict__ bv,
    __bf16* __restrict__ q, __bf16* __restrict__ kf, __bf16* __restrict__ vf)
{
    __shared__ __bf16 Xs[128 * 72];          // x tile [t_local][d], bf16
    __shared__ __bf16 Ws[3][64 * 72];        // W[e][d], bf16
    __bf16* Vtl = Xs;                         // alias: V^T [e][t_local], stride 136
    __bf16* Kst = &Ws[0][0];                  // alias after mat loop: K [t_local][d], stride 72

    const int tt  = blockIdx.x;               // 0..15 (128-token tile)
    const int bh  = blockIdx.y;               // 0..63
    const int b   = bh >> 4, h = bh & 15;
    const int t0  = tt * 128;
    const int tid = threadIdx.x;
    const int wave = tid >> 6, lane = tid & 63;
    const int m = lane & 31, hh = lane >> 5;

    // stage x (fp32 -> bf16): 128 rows x 64 cols = 2048 float4 chunks
    #pragma unroll
    for (int i = 0; i < 8; ++i) {
        const int idx = i * 256 + tid;
        const int r = idx >> 4, c = (idx & 15) * 4;
        const float4 x4 = *(const float4*)(x + ((size_t)(b * T_ + t0 + r)) * C_ + h * DH + c);
        const unsigned lo = ((unsigned)__builtin_bit_cast(unsigned short, (__bf16)x4.y) << 16)
                          | (unsigned)__builtin_bit_cast(unsigned short, (__bf16)x4.x);
        const unsigned hi = ((unsigned)__builtin_bit_cast(unsigned short, (__bf16)x4.w) << 16)
                          | (unsigned)__builtin_bit_cast(unsigned short, (__bf16)x4.z);
        *(unsigned*)&Xs[r * 72 + c]     = lo;
        *(unsigned*)&Xs[r * 72 + c + 2] = hi;
    }
    // stage weights (already bf16): 3 x 64 x 64 = 1536 uint4 chunks
    #pragma unroll
    for (int i = 0; i < 6; ++i) {
        const int idx = i * 256 + tid;
        const int mat_ = idx >> 9;            // 0..2
        const int r = (idx >> 3) & 63, c = (idx & 7) * 8;
        *(uint4*)&Ws[mat_][r * 72 + c] = *(const uint4*)(wqkv + mat_ * 4096 + r * 64 + c);
    }
    __syncthreads();

    // hoist x A-fragments (wave-private rows 32*wave + m)
    bf16x8 xf[4];
    #pragma unroll
    for (int ks = 0; ks < 4; ++ks)
        xf[ks] = *(const bf16x8*)&Xs[(wave * 32 + m) * 72 + ks * 16 + hh * 8];
    __syncthreads();   // all frag reads done before Vtl aliases Xs

    // 1/sqrt(1024) * log2(e) folded into q (attention uses exp2 directly)
    const float s32 = 0.03125f * 1.4426950408889634f;

    unsigned kpk[16];   // packed k results, staged to LDS after the mat loop

    #pragma unroll
    for (int mat = 0; mat < 3; ++mat) {
        f32x16 acc0 = {}, acc1 = {};
        #pragma unroll
        for (int ks = 0; ks < 4; ++ks) {
            const bf16x8 w0 = *(const bf16x8*)&Ws[mat][(m) * 72 + ks * 16 + hh * 8];
            const bf16x8 w1 = *(const bf16x8*)&Ws[mat][(32 + m) * 72 + ks * 16 + hh * 8];
            acc0 = MFMA32(xf[ks], w0, acc0);
            acc1 = MFMA32(xf[ks], w1, acc1);
        }
        const float* bias = (mat == 0) ? bq : (mat == 1) ? bk : bv;
        const float b0 = bias[m], b1 = bias[32 + m];
        #pragma unroll
        for (int r = 0; r < 16; ++r) {
            const int R = (r & 3) + 8 * (r >> 2) + 4 * hh;   // token row in tile
            const int tloc = wave * 32 + R;
            const float v0 = acc0[r] + b0, v1 = acc1[r] + b1;
            if (mat == 0) {
                const size_t base = ((size_t)bh * T_ + t0 + tloc) * DH;
                q[base + m]      = (__bf16)(v0 * s32);
                q[base + 32 + m] = (__bf16)(v1 * s32);
            } else if (mat == 1) {
                kpk[r] = ((unsigned)__builtin_bit_cast(unsigned short, (__bf16)v1) << 16)
                       |  (unsigned)__builtin_bit_cast(unsigned short, (__bf16)v0);
            } else {
                Vtl[(m) * 136 + tloc]      = (__bf16)v0;   // V^T [e][t_local]
                Vtl[(32 + m) * 136 + tloc] = (__bf16)v1;
            }
        }
    }
    __syncthreads();   // Ws reads done (mat loop), Vtl complete

    // stage k tile [t_local][d] into Kst (Ws area, now dead)
    #pragma unroll
    for (int r = 0; r < 16; ++r) {
        const int R = (r & 3) + 8 * (r >> 2) + 4 * hh;
        const int tloc = wave * 32 + R;
        Kst[tloc * 72 + m]      = __builtin_bit_cast(__bf16, (unsigned short)(kpk[r] & 0xffff));
        Kst[tloc * 72 + 32 + m] = __builtin_bit_cast(__bf16, (unsigned short)(kpk[r] >> 16));
    }

    // Vf fragment-major out (reads Vtl; no barrier needed vs Kst region)
    #pragma unroll
    for (int i = 0; i < 4; ++i) {
        const int idx = i * 256 + tid;
        const int ln = idx & 63, c_ = idx >> 6;           // c_ 0..15
        const int kt64l = c_ >> 3, dh = (c_ >> 2) & 1, cN = c_ & 3;
        const __bf16* src = &Vtl[(dh * 32 + (ln & 31)) * 136 + kt64l * 64 + cN * 16 + (ln >> 5) * 8];
        __bf16* dst = vf + ((((size_t)(bh * 32 + tt * 2 + kt64l) * 2 + dh) * 4 + cN) * 64 + ln) * 8;
        *(uint4*)dst = *(const uint4*)src;
    }
    __syncthreads();   // Kst visible

    // Kf fragment-major out (reads Kst)
    #pragma unroll
    for (int i = 0; i < 4; ++i) {
        const int idx = i * 256 + tid;
        const int ln = idx & 63, c_ = idx >> 6;
        const int kt64l = c_ >> 3, rh = (c_ >> 2) & 1, ks = c_ & 3;
        const __bf16* src = &Kst[(kt64l * 64 + rh * 32 + (ln & 31)) * 72 + ks * 16 + (ln >> 5) * 8];
        __bf16* dst = kf + ((((size_t)(bh * 32 + tt * 2 + kt64l) * 2 + rh) * 4 + ks) * 64 + ln) * 8;
        *(uint4*)dst = *(const uint4*)src;
    }
}

// ---------------------------------------------------------------------------
// Kernel 2: flash attention, 64 Q-ROWS PER WAVE, zero LDS.
// The frozen 89 us across rounds 5-8 tracks the load path: 1 coalesced 1KB
// load per MFMA = ~55 us/CU of TA/TD time vs 27.5 us MFMA. Holding TWO
// 32-row Q slices per wave means every K fragment feeds 2 S-MFMAs and every
// V fragment feeds 2 PV-MFMAs: load:MFMA = 0.5 (TA ~27 us, overlappable
// with MFMA). Grid (64 bh, 8 qy) = 512 blocks, 2 waves/SIMD at ~176 VGPR.
// Epilogue: register-direct Af fragment store (cvt_pk + permlane32_swap),
// verified in round 8.
// ---------------------------------------------------------------------------
__global__ __launch_bounds__(256, 2) void attn_kernel(
    const __bf16* __restrict__ q, const __bf16* __restrict__ kf,
    const __bf16* __restrict__ vf, __bf16* __restrict__ af)
{
    const int bh  = blockIdx.x;         // XCD-locality axis (id%8 == bh%8)
    const int q0  = blockIdx.y * 256;   // 256-row block tile
    const int tid = threadIdx.x;
    const int wave = tid >> 6, lane = tid & 63;
    const int m = lane & 31, h = lane >> 5;
    const int row0 = q0 + wave * 64;    // this wave's 64-row slice

    const __bf16* qb  = q  + (size_t)bh * T_ * DH;
    const __bf16* kfb = kf + (size_t)bh * (T_ * DH);   // [kt64][rh][ks][lane][8]
    const __bf16* vfb = vf + (size_t)bh * (T_ * DH);   // [kt64][dh][c ][lane][8]

    // Q fragments, both halves (one-time)
    bf16x8 qfa[4], qfb_[4];
    #pragma unroll
    for (int ks = 0; ks < 4; ++ks) {
        qfa[ks]  = *(const bf16x8*)(qb + (size_t)(row0 + m) * DH + ks * 16 + h * 8);
        qfb_[ks] = *(const bf16x8*)(qb + (size_t)(row0 + 32 + m) * DH + ks * 16 + h * 8);
    }

    f32x16 Oa0 = {}, Oa1 = {}, Ob0 = {}, Ob1 = {};   // O^T per half [d-half][q]
    float lsa = 0.f, lsb = 0.f;

    for (int kt = 0; kt < 32; ++kt) {
        const __bf16* kt_k = kfb + kt * 4096;
        const __bf16* kt_v = vfb + kt * 4096;
        #pragma unroll
        for (int rh = 0; rh < 2; ++rh) {
            bf16x8 kfr[4];
            #pragma unroll
            for (int ks = 0; ks < 4; ++ks)
                kfr[ks] = *(const bf16x8*)(kt_k + rh * 2048 + ks * 512 + lane * 8);
            // shared K fragments -> S for BOTH q-halves (2 MFMA per load)
            f32x16 Sa = {}, Sb = {};
            #pragma unroll
            for (int ks = 0; ks < 4; ++ks) {
                Sa = MFMA32(kfr[ks], qfa[ks],  Sa);
                Sb = MFMA32(kfr[ks], qfb_[ks], Sb);
            }

            #pragma unroll
            for (int cc = 0; cc < 2; ++cc) {
                const int rb = cc * 8;
                // half a softmax chunk
                float a0f = __builtin_amdgcn_exp2f(Sa[rb + 0]);
                float a1f = __builtin_amdgcn_exp2f(Sa[rb + 1]);
                float a2f = __builtin_amdgcn_exp2f(Sa[rb + 2]);
                float a3f = __builtin_amdgcn_exp2f(Sa[rb + 3]);
                float a4f = __builtin_amdgcn_exp2f(Sa[rb + 4]);
                float a5f = __builtin_amdgcn_exp2f(Sa[rb + 5]);
                float a6f = __builtin_amdgcn_exp2f(Sa[rb + 6]);
                float a7f = __builtin_amdgcn_exp2f(Sa[rb + 7]);
                lsa += ((a0f + a1f) + (a2f + a3f)) + ((a4f + a5f) + (a6f + a7f));
                unsigned pa0 = cvt_pk_bf16(a0f, a1f);
                unsigned pa1 = cvt_pk_bf16(a2f, a3f);
                unsigned pa2 = cvt_pk_bf16(a4f, a5f);
                unsigned pa3 = cvt_pk_bf16(a6f, a7f);
                asm("v_permlane32_swap_b32 %0, %1" : "+v"(pa0), "+v"(pa2));
                asm("v_permlane32_swap_b32 %0, %1" : "+v"(pa1), "+v"(pa3));
                const uint4 pwa = {pa0, pa1, pa2, pa3};
                const bf16x8 pba = __builtin_bit_cast(bf16x8, pwa);
                // half b softmax chunk
                float b0f = __builtin_amdgcn_exp2f(Sb[rb + 0]);
                float b1f = __builtin_amdgcn_exp2f(Sb[rb + 1]);
                float b2f = __builtin_amdgcn_exp2f(Sb[rb + 2]);
                float b3f = __builtin_amdgcn_exp2f(Sb[rb + 3]);
                float b4f = __builtin_amdgcn_exp2f(Sb[rb + 4]);
                float b5f = __builtin_amdgcn_exp2f(Sb[rb + 5]);
                float b6f = __builtin_amdgcn_exp2f(Sb[rb + 6]);
                float b7f = __builtin_amdgcn_exp2f(Sb[rb + 7]);
                lsb += ((b0f + b1f) + (b2f + b3f)) + ((b4f + b5f) + (b6f + b7f));
                unsigned pb0 = cvt_pk_bf16(b0f, b1f);
                unsigned pb1 = cvt_pk_bf16(b2f, b3f);
                unsigned pb2 = cvt_pk_bf16(b4f, b5f);
                unsigned pb3 = cvt_pk_bf16(b6f, b7f);
                asm("v_permlane32_swap_b32 %0, %1" : "+v"(pb0), "+v"(pb2));
                asm("v_permlane32_swap_b32 %0, %1" : "+v"(pb1), "+v"(pb3));
                const uint4 pwb = {pb0, pb1, pb2, pb3};
                const bf16x8 pbb = __builtin_bit_cast(bf16x8, pwb);

                // shared V fragments -> PV for both halves (2 MFMA per load)
                const int c = rh * 2 + cc;          // kv 16-slot
                const bf16x8 v0 = *(const bf16x8*)(kt_v + c * 512 + lane * 8);
                const bf16x8 v1 = *(const bf16x8*)(kt_v + 2048 + c * 512 + lane * 8);
                Oa0 = MFMA32(v0, pba, Oa0);
                Oa1 = MFMA32(v1, pba, Oa1);
                Ob0 = MFMA32(v0, pbb, Ob0);
                Ob1 = MFMA32(v1, pbb, Ob1);
            }
        }
    }

    // l reduction: lanes l, l+32 hold complementary kv rows of the same q
    lsa += __shfl_xor(lsa, 32);
    lsb += __shfl_xor(lsb, 32);
    const float linva = 1.0f / lsa, linvb = 1.0f / lsb;

    // register-direct Af fragment stores (round-8 verified recipe), per half
    const int qt = row0 >> 7;                 // 128-row tile index
    const int wv_a = (row0 >> 5) & 3;         // 32-row slice within tile
    __bf16* ab_a = af + ((size_t)(bh * 16 + qt)) * 8192 + wv_a * 2048 + lane * 8;
    __bf16* ab_b = ab_a + 2048;               // half b is the next 32-row slice
    #pragma unroll
    for (int ks = 0; ks < 4; ++ks) {
        {
            const f32x16& Og = (ks < 2) ? Oa0 : Oa1;
            const int rb = (ks & 1) * 8;
            unsigned a0 = cvt_pk_bf16(Og[rb + 0] * linva, Og[rb + 1] * linva);
            unsigned a1 = cvt_pk_bf16(Og[rb + 2] * linva, Og[rb + 3] * linva);
            unsigned b0 = cvt_pk_bf16(Og[rb + 4] * linva, Og[rb + 5] * linva);
            unsigned b1 = cvt_pk_bf16(Og[rb + 6] * linva, Og[rb + 7] * linva);
            asm("v_permlane32_swap_b32 %0, %1" : "+v"(a0), "+v"(b0));
            asm("v_permlane32_swap_b32 %0, %1" : "+v"(a1), "+v"(b1));
            const uint4 pw = {a0, a1, b0, b1};
            *(uint4*)(ab_a + ks * 512) = pw;
        }
        {
            const f32x16& Og = (ks < 2) ? Ob0 : Ob1;
            const int rb = (ks & 1) * 8;
            unsigned a0 = cvt_pk_bf16(Og[rb + 0] * linvb, Og[rb + 1] * linvb);
            unsigned a1 = cvt_pk_bf16(Og[rb + 2] * linvb, Og[rb + 3] * linvb);
            unsigned b0 = cvt_pk_bf16(Og[rb + 4] * linvb, Og[rb + 5] * linvb);
            unsigned b1 = cvt_pk_bf16(Og[rb + 6] * linvb, Og[rb + 7] * linvb);
            asm("v_permlane32_swap_b32 %0, %1" : "+v"(a0), "+v"(b0));
            asm("v_permlane32_swap_b32 %0, %1" : "+v"(a1), "+v"(b1));
            const uint4 pw = {a0, a1, b0, b1};
            *(uint4*)(ab_b + ks * 512) = pw;
        }
    }
}

// ---------------------------------------------------------------------------
// Kernel 2.5: Wp fp32 -> bf16 FRAGMENT-MAJOR, coalesced via LDS transpose.
// 128 blocks, each one (eb,cb) tile: coalesced f32 row reads -> LDS ->
// fragment-order 16B writes (replaces the scattered 32B-granule reads).
// ---------------------------------------------------------------------------
__global__ __launch_bounds__(256) void wpconv_kernel(
    const float* __restrict__ Wp, __bf16* __restrict__ wpf)
{
    __shared__ __bf16 Bs[128 * 72];

    const int t  = blockIdx.x;            // 0..127
    const int eb = t >> 4, cb = t & 15;
    const int tid = threadIdx.x;

    // read 128 e-rows x 64 c-cols f32, coalesced; convert; stage to LDS
    #pragma unroll
    for (int i = 0; i < 8; ++i) {
        const int idx = i * 256 + tid;
        const int r = idx >> 4, c = (idx & 15) * 4;
        const float4 w4 = *(const float4*)(Wp + (size_t)(eb * 128 + r) * C_ + cb * 64 + c);
        const unsigned lo = ((unsigned)__builtin_bit_cast(unsigned short, (__bf16)w4.y) << 16)
                          | (unsigned)__builtin_bit_cast(unsigned short, (__bf16)w4.x);
        const unsigned hi = ((unsigned)__builtin_bit_cast(unsigned short, (__bf16)w4.w) << 16)
                          | (unsigned)__builtin_bit_cast(unsigned short, (__bf16)w4.z);
        *(unsigned*)&Bs[r * 72 + c]     = lo;
        *(unsigned*)&Bs[r * 72 + c + 2] = hi;
    }
    __syncthreads();

    // fragment-major out: 16 chunks (n*4+ks) x 64 lanes = 1024 uint4 / 256 thr
    #pragma unroll
    for (int i = 0; i < 4; ++i) {
        const int idx = i * 256 + tid;
        const int ln = idx & 63, c_ = idx >> 6;       // c_ = n*4+ks
        const int n = c_ >> 2, ks = c_ & 3;
        const __bf16* src = &Bs[(n * 32 + (ln & 31)) * 72 + ks * 16 + (ln >> 5) * 8];
        *(uint4*)(wpf + (size_t)eb * 131072 + cb * 8192 + c_ * 512 + ln * 8)
            = *(const uint4*)src;
    }
}

// ---------------------------------------------------------------------------
// Kernel 3: output projection (UNCHANGED from round 8).
// ---------------------------------------------------------------------------
__global__ __launch_bounds__(256) void proj_kernel(
    const __bf16* __restrict__ af,     // Af fragment-major
    const __bf16* __restrict__ wpf,    // Wpf fragment-major
    const float* __restrict__ bp,
    float* __restrict__ out)
{
    const int tb2 = blockIdx.x, eb = blockIdx.y;
    const int tid = threadIdx.x;
    const int wave = tid >> 6, lane = tid & 63;
    const int m = lane & 31, h = lane >> 5;
    const int b = tb2 >> 5, rem = tb2 & 31;
    const int qtile = rem >> 1, half = rem & 1;
    const int wv = half * 2 + (wave & 1);   // 32-row token slice
    const int eh = wave >> 1;               // 64-col e half
    const int e0 = eb * 128;

    const __bf16* abase = af + ((size_t)(b * 256 + qtile)) * 8192
                             + wv * 2048 + lane * 8;
    const __bf16* wbase = wpf + (size_t)eb * 131072 + eh * 4096 + lane * 8;

    f32x16 acc[2] = {f32x16{}, f32x16{}};

    for (int cb = 0; cb < 16; ++cb) {
        const __bf16* ap = abase + (size_t)cb * 131072;   // 16 qtiles * 8192
        const __bf16* wp = wbase + (size_t)cb * 8192;
        bf16x8 afr[4];
        #pragma unroll
        for (int ks = 0; ks < 4; ++ks)
            afr[ks] = *(const bf16x8*)(ap + ks * 512);
        #pragma unroll
        for (int n = 0; n < 2; ++n) {
            #pragma unroll
            for (int ks = 0; ks < 4; ++ks) {
                const bf16x8 bf = *(const bf16x8*)(wp + (n * 4 + ks) * 512);
                acc[n] = MFMA32(afr[ks], bf, acc[n]);
            }
        }
    }

    const int tokbase = b * T_ + qtile * 128 + wv * 32;
    #pragma unroll
    for (int n = 0; n < 2; ++n) {
        const int e = e0 + (eh * 2 + n) * 32 + m;
        const float bias = bp[e];
        #pragma unroll
        for (int r = 0; r < 16; ++r) {
            const int R = (r & 3) + 8 * (r >> 2) + 4 * h;
            out[(size_t)(tokbase + R) * C_ + e] = acc[n][r] + bias;
        }
    }
}

// ---------------------------------------------------------------------------
// Workspace (bf16): q | kf | vf | af, each B*H*T*DH = 8388608 elems
// -> 64 MiB total. wqkv (24 KB) reuses af region (dead until attn);
// wpf (2 MiB) reuses q region (dead after attn).
// ---------------------------------------------------------------------------
extern "C" void kernel_launch(void* const* d_in, const int* in_sizes, int n_in,
                              void* d_out, int out_size, void* d_ws, size_t ws_size,
                              hipStream_t stream)
{
    const float* x  = (const float*)d_in[0];
    const float* Wq = (const float*)d_in[1];
    const float* bq = (const float*)d_in[2];
    const float* Wk = (const float*)d_in[3];
    const float* bk = (const float*)d_in[4];
    const float* Wv = (const float*)d_in[5];
    const float* bv = (const float*)d_in[6];
    const float* Wp = (const float*)d_in[7];
    const float* bp = (const float*)d_in[8];

    const size_t N = (size_t)BH * T_ * DH;
    __bf16* qws  = (__bf16*)d_ws;
    __bf16* kws  = qws + N;
    __bf16* vtws = kws + N;
    __bf16* aws  = vtws + N;
    __bf16* wqkv = aws;                 // dead until attn writes aws
    __bf16* wpf  = qws;                 // q dead after attn

    wconv_kernel<<<dim3(12), 256, 0, stream>>>(Wq, Wk, Wv, wqkv);
    qkv_kernel<<<dim3(16, 64), 256, 0, stream>>>(
        x, wqkv, bq, bk, bv, qws, kws, vtws);
    attn_kernel<<<dim3(64, 8), 256, 0, stream>>>(qws, kws, vtws, aws);
    wpconv_kernel<<<dim3(128), 256, 0, stream>>>(Wp, wpf);
    proj_kernel<<<dim3(128, 8), 256, 0, stream>>>(aws, wpf, bp, (float*)d_out);
}

// Round 10
// 225.805 us; speedup vs baseline: 1.0222x; 1.0222x over previous
//
#include <hip/hip_runtime.h>
#include <hip/hip_bf16.h>
#include <cstddef>

// Problem constants (SelfAttention: B=4, T=2048, H=16, Dh=64, C=1024)
#define B_  4
#define T_  2048
#define H_  16
#define DH  64
#define C_  1024
#define BH  64    // B_*H_

typedef float  f32x16 __attribute__((ext_vector_type(16)));
typedef __bf16 bf16x8 __attribute__((ext_vector_type(8)));
typedef __bf16 bf16x4 __attribute__((ext_vector_type(4)));

#define MFMA32(a, b, c) __builtin_amdgcn_mfma_f32_32x32x16_bf16(a, b, c, 0, 0, 0)

// mfma_f32_32x32x16_bf16 layouts (cdna4_isa / m74,m101 verified C/D):
//   A[m][k]: m = lane&31, k = (lane>>5)*8 + j   (8 bf16 per lane, b128)
//   B[k][n]: n = lane&31, k = (lane>>5)*8 + j
//   C/D:     col = lane&31, row = (reg&3) + 8*(reg>>2) + 4*(lane>>5)
//
// FRAGMENT-MAJOR global layouts (a fragment load = base + lane*16B -> one
// coalesced 1KB transaction per wave):
//   Kf[bh][kt64][rh][ks][lane][8]   (K rows,   QK^T A-operand)
//   Vf[bh][kt64][dh][c ][lane][8]   (V^T rows, PV A-operand)
//   Af[(bh*16)+qt][wv][ks][lane][8] (attn out, proj A-operand)
//   Wpf[eb][cb][n][ks][lane][8]     (Wp,      proj B-operand)

__device__ __forceinline__ unsigned cvt_pk_bf16(float lo, float hi) {
    unsigned r;
    asm("v_cvt_pk_bf16_f32 %0, %1, %2" : "=v"(r) : "v"(lo), "v"(hi));
    return r;
}

// ---------------------------------------------------------------------------
// Kernel 1: QKV projection, bf16 MFMA. Block = (128-token tile, one head).
// Inline f32->bf16 weight staging (R5-proven; the separate wconv kernel and
// pre-converted-weight read path measured net-slower in rounds 6-9).
// q written [bh][t][d] with (1/sqrt(C))*log2(e) folded; k/v fragment-major.
// Optional epilogue (wpf != nullptr): each of the 1024 blocks converts 128
// of Wp's 131072 fragment-chunks -> absorbs the standalone wpconv kernel.
// ---------------------------------------------------------------------------
__global__ __launch_bounds__(256) void qkv_kernel(
    const float* __restrict__ x,
    const float* __restrict__ Wq, const float* __restrict__ bq,
    const float* __restrict__ Wk, const float* __restrict__ bk,
    const float* __restrict__ Wv, const float* __restrict__ bv,
    __bf16* __restrict__ q, __bf16* __restrict__ kf, __bf16* __restrict__ vf,
    const float* __restrict__ Wp, __bf16* __restrict__ wpf)
{
    __shared__ __bf16 Xs[128 * 72];          // x tile [t_local][d], bf16
    __shared__ __bf16 Ws[3][64 * 72];        // W[e][d], bf16
    __bf16* Vtl = Xs;                         // alias: V^T [e][t_local], stride 136
    __bf16* Kst = &Ws[0][0];                  // alias after mat loop: K [t_local][d], stride 72

    const int tt  = blockIdx.x;               // 0..15 (128-token tile)
    const int bh  = blockIdx.y;               // 0..63
    const int b   = bh >> 4, h = bh & 15;
    const int t0  = tt * 128;
    const int tid = threadIdx.x;
    const int wave = tid >> 6, lane = tid & 63;
    const int m = lane & 31, hh = lane >> 5;

    // stage x (fp32 -> bf16): 128 rows x 64 cols = 2048 float4 chunks
    #pragma unroll
    for (int i = 0; i < 8; ++i) {
        const int idx = i * 256 + tid;
        const int r = idx >> 4, c = (idx & 15) * 4;
        const float4 x4 = *(const float4*)(x + ((size_t)(b * T_ + t0 + r)) * C_ + h * DH + c);
        const unsigned lo = ((unsigned)__builtin_bit_cast(unsigned short, (__bf16)x4.y) << 16)
                          | (unsigned)__builtin_bit_cast(unsigned short, (__bf16)x4.x);
        const unsigned hi = ((unsigned)__builtin_bit_cast(unsigned short, (__bf16)x4.w) << 16)
                          | (unsigned)__builtin_bit_cast(unsigned short, (__bf16)x4.z);
        *(unsigned*)&Xs[r * 72 + c]     = lo;
        *(unsigned*)&Xs[r * 72 + c + 2] = hi;
    }
    // stage weights (fp32 -> bf16): 3 x 1024 float4 chunks (R5 inline path)
    #pragma unroll
    for (int i = 0; i < 4; ++i) {
        const int idx = i * 256 + tid;
        const int r = idx >> 4, c = (idx & 15) * 4;
        const float* wsrc[3] = {Wq, Wk, Wv};
        #pragma unroll
        for (int wv_ = 0; wv_ < 3; ++wv_) {
            const float4 w4 = *(const float4*)(wsrc[wv_] + r * 64 + c);
            const unsigned lo = ((unsigned)__builtin_bit_cast(unsigned short, (__bf16)w4.y) << 16)
                              | (unsigned)__builtin_bit_cast(unsigned short, (__bf16)w4.x);
            const unsigned hi = ((unsigned)__builtin_bit_cast(unsigned short, (__bf16)w4.w) << 16)
                              | (unsigned)__builtin_bit_cast(unsigned short, (__bf16)w4.z);
            *(unsigned*)&Ws[wv_][r * 72 + c]     = lo;
            *(unsigned*)&Ws[wv_][r * 72 + c + 2] = hi;
        }
    }
    __syncthreads();

    // hoist x A-fragments (wave-private rows 32*wave + m)
    bf16x8 xf[4];
    #pragma unroll
    for (int ks = 0; ks < 4; ++ks)
        xf[ks] = *(const bf16x8*)&Xs[(wave * 32 + m) * 72 + ks * 16 + hh * 8];
    __syncthreads();   // all frag reads done before Vtl aliases Xs

    // 1/sqrt(1024) * log2(e) folded into q (attention uses exp2 directly)
    const float s32 = 0.03125f * 1.4426950408889634f;

    unsigned kpk[16];   // packed k results, staged to LDS after the mat loop

    #pragma unroll
    for (int mat = 0; mat < 3; ++mat) {
        f32x16 acc0 = {}, acc1 = {};
        #pragma unroll
        for (int ks = 0; ks < 4; ++ks) {
            const bf16x8 w0 = *(const bf16x8*)&Ws[mat][(m) * 72 + ks * 16 + hh * 8];
            const bf16x8 w1 = *(const bf16x8*)&Ws[mat][(32 + m) * 72 + ks * 16 + hh * 8];
            acc0 = MFMA32(xf[ks], w0, acc0);
            acc1 = MFMA32(xf[ks], w1, acc1);
        }
        const float* bias = (mat == 0) ? bq : (mat == 1) ? bk : bv;
        const float b0 = bias[m], b1 = bias[32 + m];
        #pragma unroll
        for (int r = 0; r < 16; ++r) {
            const int R = (r & 3) + 8 * (r >> 2) + 4 * hh;   // token row in tile
            const int tloc = wave * 32 + R;
            const float v0 = acc0[r] + b0, v1 = acc1[r] + b1;
            if (mat == 0) {
                const size_t base = ((size_t)bh * T_ + t0 + tloc) * DH;
                q[base + m]      = (__bf16)(v0 * s32);
                q[base + 32 + m] = (__bf16)(v1 * s32);
            } else if (mat == 1) {
                kpk[r] = ((unsigned)__builtin_bit_cast(unsigned short, (__bf16)v1) << 16)
                       |  (unsigned)__builtin_bit_cast(unsigned short, (__bf16)v0);
            } else {
                Vtl[(m) * 136 + tloc]      = (__bf16)v0;   // V^T [e][t_local]
                Vtl[(32 + m) * 136 + tloc] = (__bf16)v1;
            }
        }
    }
    __syncthreads();   // Ws reads done (mat loop), Vtl complete

    // stage k tile [t_local][d] into Kst (Ws area, now dead)
    #pragma unroll
    for (int r = 0; r < 16; ++r) {
        const int R = (r & 3) + 8 * (r >> 2) + 4 * hh;
        const int tloc = wave * 32 + R;
        Kst[tloc * 72 + m]      = __builtin_bit_cast(__bf16, (unsigned short)(kpk[r] & 0xffff));
        Kst[tloc * 72 + 32 + m] = __builtin_bit_cast(__bf16, (unsigned short)(kpk[r] >> 16));
    }

    // Vf fragment-major out (reads Vtl; no barrier needed vs Kst region)
    #pragma unroll
    for (int i = 0; i < 4; ++i) {
        const int idx = i * 256 + tid;
        const int ln = idx & 63, c_ = idx >> 6;           // c_ 0..15
        const int kt64l = c_ >> 3, dh = (c_ >> 2) & 1, cN = c_ & 3;
        const __bf16* src = &Vtl[(dh * 32 + (ln & 31)) * 136 + kt64l * 64 + cN * 16 + (ln >> 5) * 8];
        __bf16* dst = vf + ((((size_t)(bh * 32 + tt * 2 + kt64l) * 2 + dh) * 4 + cN) * 64 + ln) * 8;
        *(uint4*)dst = *(const uint4*)src;
    }
    __syncthreads();   // Kst visible

    // Kf fragment-major out (reads Kst)
    #pragma unroll
    for (int i = 0; i < 4; ++i) {
        const int idx = i * 256 + tid;
        const int ln = idx & 63, c_ = idx >> 6;
        const int kt64l = c_ >> 3, rh = (c_ >> 2) & 1, ks = c_ & 3;
        const __bf16* src = &Kst[(kt64l * 64 + rh * 32 + (ln & 31)) * 72 + ks * 16 + (ln >> 5) * 8];
        __bf16* dst = kf + ((((size_t)(bh * 32 + tt * 2 + kt64l) * 2 + rh) * 4 + ks) * 64 + ln) * 8;
        *(uint4*)dst = *(const uint4*)src;
    }

    // optional Wp fragment-major conversion: 128 chunks per block (tid<128)
    if (wpf != nullptr && tid < 128) {
        const int ci = (bh * 16 + tt) * 128 + tid;     // chunk 0..131071
        const int ln = ci & 63;
        const int ks = (ci >> 6) & 3;
        const int n  = (ci >> 8) & 3;
        const int cb = (ci >> 10) & 15;
        const int eb = ci >> 14;
        const int row = eb * 128 + n * 32 + (ln & 31);
        const int col = cb * 64 + ks * 16 + (ln >> 5) * 8;
        const float4 w0 = *(const float4*)(Wp + (size_t)row * C_ + col);
        const float4 w1 = *(const float4*)(Wp + (size_t)row * C_ + col + 4);
        uint4 p;
        p.x = ((unsigned)__builtin_bit_cast(unsigned short, (__bf16)w0.y) << 16)
            |  (unsigned)__builtin_bit_cast(unsigned short, (__bf16)w0.x);
        p.y = ((unsigned)__builtin_bit_cast(unsigned short, (__bf16)w0.w) << 16)
            |  (unsigned)__builtin_bit_cast(unsigned short, (__bf16)w0.z);
        p.z = ((unsigned)__builtin_bit_cast(unsigned short, (__bf16)w1.y) << 16)
            |  (unsigned)__builtin_bit_cast(unsigned short, (__bf16)w1.x);
        p.w = ((unsigned)__builtin_bit_cast(unsigned short, (__bf16)w1.w) << 16)
            |  (unsigned)__builtin_bit_cast(unsigned short, (__bf16)w1.z);
        *(uint4*)(wpf + (size_t)ci * 8) = p;
    }
}

// ---------------------------------------------------------------------------
// Kernel 2: flash attention (UNCHANGED from round 9 -- the 89 us control).
// 64 q-rows/wave, zero LDS, fragment-major coalesced loads, register-direct
// Af fragment stores. Grid (64 bh, 8 qy).
// ---------------------------------------------------------------------------
__global__ __launch_bounds__(256, 2) void attn_kernel(
    const __bf16* __restrict__ q, const __bf16* __restrict__ kf,
    const __bf16* __restrict__ vf, __bf16* __restrict__ af)
{
    const int bh  = blockIdx.x;         // XCD-locality axis (id%8 == bh%8)
    const int q0  = blockIdx.y * 256;   // 256-row block tile
    const int tid = threadIdx.x;
    const int wave = tid >> 6, lane = tid & 63;
    const int m = lane & 31, h = lane >> 5;
    const int row0 = q0 + wave * 64;    // this wave's 64-row slice

    const __bf16* qb  = q  + (size_t)bh * T_ * DH;
    const __bf16* kfb = kf + (size_t)bh * (T_ * DH);   // [kt64][rh][ks][lane][8]
    const __bf16* vfb = vf + (size_t)bh * (T_ * DH);   // [kt64][dh][c ][lane][8]

    // Q fragments, both halves (one-time)
    bf16x8 qfa[4], qfb_[4];
    #pragma unroll
    for (int ks = 0; ks < 4; ++ks) {
        qfa[ks]  = *(const bf16x8*)(qb + (size_t)(row0 + m) * DH + ks * 16 + h * 8);
        qfb_[ks] = *(const bf16x8*)(qb + (size_t)(row0 + 32 + m) * DH + ks * 16 + h * 8);
    }

    f32x16 Oa0 = {}, Oa1 = {}, Ob0 = {}, Ob1 = {};   // O^T per half [d-half][q]
    float lsa = 0.f, lsb = 0.f;

    for (int kt = 0; kt < 32; ++kt) {
        const __bf16* kt_k = kfb + kt * 4096;
        const __bf16* kt_v = vfb + kt * 4096;
        #pragma unroll
        for (int rh = 0; rh < 2; ++rh) {
            bf16x8 kfr[4];
            #pragma unroll
            for (int ks = 0; ks < 4; ++ks)
                kfr[ks] = *(const bf16x8*)(kt_k + rh * 2048 + ks * 512 + lane * 8);
            // shared K fragments -> S for BOTH q-halves (2 MFMA per load)
            f32x16 Sa = {}, Sb = {};
            #pragma unroll
            for (int ks = 0; ks < 4; ++ks) {
                Sa = MFMA32(kfr[ks], qfa[ks],  Sa);
                Sb = MFMA32(kfr[ks], qfb_[ks], Sb);
            }

            #pragma unroll
            for (int cc = 0; cc < 2; ++cc) {
                const int rb = cc * 8;
                // half a softmax chunk
                float a0f = __builtin_amdgcn_exp2f(Sa[rb + 0]);
                float a1f = __builtin_amdgcn_exp2f(Sa[rb + 1]);
                float a2f = __builtin_amdgcn_exp2f(Sa[rb + 2]);
                float a3f = __builtin_amdgcn_exp2f(Sa[rb + 3]);
                float a4f = __builtin_amdgcn_exp2f(Sa[rb + 4]);
                float a5f = __builtin_amdgcn_exp2f(Sa[rb + 5]);
                float a6f = __builtin_amdgcn_exp2f(Sa[rb + 6]);
                float a7f = __builtin_amdgcn_exp2f(Sa[rb + 7]);
                lsa += ((a0f + a1f) + (a2f + a3f)) + ((a4f + a5f) + (a6f + a7f));
                unsigned pa0 = cvt_pk_bf16(a0f, a1f);
                unsigned pa1 = cvt_pk_bf16(a2f, a3f);
                unsigned pa2 = cvt_pk_bf16(a4f, a5f);
                unsigned pa3 = cvt_pk_bf16(a6f, a7f);
                asm("v_permlane32_swap_b32 %0, %1" : "+v"(pa0), "+v"(pa2));
                asm("v_permlane32_swap_b32 %0, %1" : "+v"(pa1), "+v"(pa3));
                const uint4 pwa = {pa0, pa1, pa2, pa3};
                const bf16x8 pba = __builtin_bit_cast(bf16x8, pwa);
                // half b softmax chunk
                float b0f = __builtin_amdgcn_exp2f(Sb[rb + 0]);
                float b1f = __builtin_amdgcn_exp2f(Sb[rb + 1]);
                float b2f = __builtin_amdgcn_exp2f(Sb[rb + 2]);
                float b3f = __builtin_amdgcn_exp2f(Sb[rb + 3]);
                float b4f = __builtin_amdgcn_exp2f(Sb[rb + 4]);
                float b5f = __builtin_amdgcn_exp2f(Sb[rb + 5]);
                float b6f = __builtin_amdgcn_exp2f(Sb[rb + 6]);
                float b7f = __builtin_amdgcn_exp2f(Sb[rb + 7]);
                lsb += ((b0f + b1f) + (b2f + b3f)) + ((b4f + b5f) + (b6f + b7f));
                unsigned pb0 = cvt_pk_bf16(b0f, b1f);
                unsigned pb1 = cvt_pk_bf16(b2f, b3f);
                unsigned pb2 = cvt_pk_bf16(b4f, b5f);
                unsigned pb3 = cvt_pk_bf16(b6f, b7f);
                asm("v_permlane32_swap_b32 %0, %1" : "+v"(pb0), "+v"(pb2));
                asm("v_permlane32_swap_b32 %0, %1" : "+v"(pb1), "+v"(pb3));
                const uint4 pwb = {pb0, pb1, pb2, pb3};
                const bf16x8 pbb = __builtin_bit_cast(bf16x8, pwb);

                // shared V fragments -> PV for both halves (2 MFMA per load)
                const int c = rh * 2 + cc;          // kv 16-slot
                const bf16x8 v0 = *(const bf16x8*)(kt_v + c * 512 + lane * 8);
                const bf16x8 v1 = *(const bf16x8*)(kt_v + 2048 + c * 512 + lane * 8);
                Oa0 = MFMA32(v0, pba, Oa0);
                Oa1 = MFMA32(v1, pba, Oa1);
                Ob0 = MFMA32(v0, pbb, Ob0);
                Ob1 = MFMA32(v1, pbb, Ob1);
            }
        }
    }

    // l reduction: lanes l, l+32 hold complementary kv rows of the same q
    lsa += __shfl_xor(lsa, 32);
    lsb += __shfl_xor(lsb, 32);
    const float linva = 1.0f / lsa, linvb = 1.0f / lsb;

    // register-direct Af fragment stores, per half
    const int qt = row0 >> 7;                 // 128-row tile index
    const int wv_a = (row0 >> 5) & 3;         // 32-row slice within tile
    __bf16* ab_a = af + ((size_t)(bh * 16 + qt)) * 8192 + wv_a * 2048 + lane * 8;
    __bf16* ab_b = ab_a + 2048;               // half b is the next 32-row slice
    #pragma unroll
    for (int ks = 0; ks < 4; ++ks) {
        {
            const f32x16& Og = (ks < 2) ? Oa0 : Oa1;
            const int rb = (ks & 1) * 8;
            unsigned a0 = cvt_pk_bf16(Og[rb + 0] * linva, Og[rb + 1] * linva);
            unsigned a1 = cvt_pk_bf16(Og[rb + 2] * linva, Og[rb + 3] * linva);
            unsigned b0 = cvt_pk_bf16(Og[rb + 4] * linva, Og[rb + 5] * linva);
            unsigned b1 = cvt_pk_bf16(Og[rb + 6] * linva, Og[rb + 7] * linva);
            asm("v_permlane32_swap_b32 %0, %1" : "+v"(a0), "+v"(b0));
            asm("v_permlane32_swap_b32 %0, %1" : "+v"(a1), "+v"(b1));
            const uint4 pw = {a0, a1, b0, b1};
            *(uint4*)(ab_a + ks * 512) = pw;
        }
        {
            const f32x16& Og = (ks < 2) ? Ob0 : Ob1;
            const int rb = (ks & 1) * 8;
            unsigned a0 = cvt_pk_bf16(Og[rb + 0] * linvb, Og[rb + 1] * linvb);
            unsigned a1 = cvt_pk_bf16(Og[rb + 2] * linvb, Og[rb + 3] * linvb);
            unsigned b0 = cvt_pk_bf16(Og[rb + 4] * linvb, Og[rb + 5] * linvb);
            unsigned b1 = cvt_pk_bf16(Og[rb + 6] * linvb, Og[rb + 7] * linvb);
            asm("v_permlane32_swap_b32 %0, %1" : "+v"(a0), "+v"(b0));
            asm("v_permlane32_swap_b32 %0, %1" : "+v"(a1), "+v"(b1));
            const uint4 pw = {a0, a1, b0, b1};
            *(uint4*)(ab_b + ks * 512) = pw;
        }
    }
}

// ---------------------------------------------------------------------------
// Kernel 2.5 (FALLBACK ONLY, when workspace < 66 MiB): standalone Wp
// fragment-major conversion (R8 version, 512 blocks).
// ---------------------------------------------------------------------------
__global__ __launch_bounds__(256) void wpconv_kernel(
    const float* __restrict__ Wp, __bf16* __restrict__ wpf)
{
    const int ci = blockIdx.x * 256 + threadIdx.x;     // chunk 0..131071
    const int ln = ci & 63;
    const int ks = (ci >> 6) & 3;
    const int n  = (ci >> 8) & 3;
    const int cb = (ci >> 10) & 15;
    const int eb = ci >> 14;
    const int row = eb * 128 + n * 32 + (ln & 31);
    const int col = cb * 64 + ks * 16 + (ln >> 5) * 8;
    const float4 w0 = *(const float4*)(Wp + (size_t)row * C_ + col);
    const float4 w1 = *(const float4*)(Wp + (size_t)row * C_ + col + 4);
    uint4 p;
    p.x = ((unsigned)__builtin_bit_cast(unsigned short, (__bf16)w0.y) << 16)
        |  (unsigned)__builtin_bit_cast(unsigned short, (__bf16)w0.x);
    p.y = ((unsigned)__builtin_bit_cast(unsigned short, (__bf16)w0.w) << 16)
        |  (unsigned)__builtin_bit_cast(unsigned short, (__bf16)w0.z);
    p.z = ((unsigned)__builtin_bit_cast(unsigned short, (__bf16)w1.y) << 16)
        |  (unsigned)__builtin_bit_cast(unsigned short, (__bf16)w1.x);
    p.w = ((unsigned)__builtin_bit_cast(unsigned short, (__bf16)w1.w) << 16)
        |  (unsigned)__builtin_bit_cast(unsigned short, (__bf16)w1.z);
    *(uint4*)(wpf + (size_t)ci * 8) = p;
}

// ---------------------------------------------------------------------------
// Kernel 3: output projection (UNCHANGED from round 8).
// ---------------------------------------------------------------------------
__global__ __launch_bounds__(256) void proj_kernel(
    const __bf16* __restrict__ af,     // Af fragment-major
    const __bf16* __restrict__ wpf,    // Wpf fragment-major
    const float* __restrict__ bp,
    float* __restrict__ out)
{
    const int tb2 = blockIdx.x, eb = blockIdx.y;
    const int tid = threadIdx.x;
    const int wave = tid >> 6, lane = tid & 63;
    const int m = lane & 31, h = lane >> 5;
    const int b = tb2 >> 5, rem = tb2 & 31;
    const int qtile = rem >> 1, half = rem & 1;
    const int wv = half * 2 + (wave & 1);   // 32-row token slice
    const int eh = wave >> 1;               // 64-col e half
    const int e0 = eb * 128;

    const __bf16* abase = af + ((size_t)(b * 256 + qtile)) * 8192
                             + wv * 2048 + lane * 8;
    const __bf16* wbase = wpf + (size_t)eb * 131072 + eh * 4096 + lane * 8;

    f32x16 acc[2] = {f32x16{}, f32x16{}};

    for (int cb = 0; cb < 16; ++cb) {
        const __bf16* ap = abase + (size_t)cb * 131072;   // 16 qtiles * 8192
        const __bf16* wp = wbase + (size_t)cb * 8192;
        bf16x8 afr[4];
        #pragma unroll
        for (int ks = 0; ks < 4; ++ks)
            afr[ks] = *(const bf16x8*)(ap + ks * 512);
        #pragma unroll
        for (int n = 0; n < 2; ++n) {
            #pragma unroll
            for (int ks = 0; ks < 4; ++ks) {
                const bf16x8 bf = *(const bf16x8*)(wp + (n * 4 + ks) * 512);
                acc[n] = MFMA32(afr[ks], bf, acc[n]);
            }
        }
    }

    const int tokbase = b * T_ + qtile * 128 + wv * 32;
    #pragma unroll
    for (int n = 0; n < 2; ++n) {
        const int e = e0 + (eh * 2 + n) * 32 + m;
        const float bias = bp[e];
        #pragma unroll
        for (int r = 0; r < 16; ++r) {
            const int R = (r & 3) + 8 * (r >> 2) + 4 * h;
            out[(size_t)(tokbase + R) * C_ + e] = acc[n][r] + bias;
        }
    }
}

// ---------------------------------------------------------------------------
// Workspace (bf16): q | kf | vf | af, each B*H*T*DH = 8388608 elems = 64 MiB.
// Roomy path (ws >= 66 MiB): wpf lives at d_ws + 4N, converted inside qkv ->
// 3 kernels total. Fallback: wpf aliases q (dead after attn), standalone
// wpconv after attn -> 4 kernels.
// ---------------------------------------------------------------------------
extern "C" void kernel_launch(void* const* d_in, const int* in_sizes, int n_in,
                              void* d_out, int out_size, void* d_ws, size_t ws_size,
                              hipStream_t stream)
{
    const float* x  = (const float*)d_in[0];
    const float* Wq = (const float*)d_in[1];
    const float* bq = (const float*)d_in[2];
    const float* Wk = (const float*)d_in[3];
    const float* bk = (const float*)d_in[4];
    const float* Wv = (const float*)d_in[5];
    const float* bv = (const float*)d_in[6];
    const float* Wp = (const float*)d_in[7];
    const float* bp = (const float*)d_in[8];

    const size_t N = (size_t)BH * T_ * DH;
    __bf16* qws  = (__bf16*)d_ws;
    __bf16* kws  = qws + N;
    __bf16* vtws = kws + N;
    __bf16* aws  = vtws + N;

    const size_t need = 4 * N * sizeof(__bf16) + (size_t)C_ * C_ * sizeof(__bf16);
    const bool roomy = ws_size >= need;
    __bf16* wpf = roomy ? (aws + N) : qws;    // fallback: q dead after attn

    qkv_kernel<<<dim3(16, 64), 256, 0, stream>>>(
        x, Wq, bq, Wk, bk, Wv, bv, qws, kws, vtws,
        Wp, roomy ? wpf : nullptr);
    attn_kernel<<<dim3(64, 8), 256, 0, stream>>>(qws, kws, vtws, aws);
    if (!roomy)
        wpconv_kernel<<<dim3(512), 256, 0, stream>>>(Wp, wpf);
    proj_kernel<<<dim3(128, 8), 256, 0, stream>>>(aws, wpf, bp, (float*)d_out);
}

// Round 12
// 222.218 us; speedup vs baseline: 1.0387x; 1.0161x over previous
//
#include <hip/hip_runtime.h>
#include <hip/hip_bf16.h>
#include <cstddef>

// Problem constants (SelfAttention: B=4, T=2048, H=16, Dh=64, C=1024)
#define B_  4
#define T_  2048
#define H_  16
#define DH  64
#define C_  1024
#define BH  64    // B_*H_

typedef float  f32x16 __attribute__((ext_vector_type(16)));
typedef __bf16 bf16x8 __attribute__((ext_vector_type(8)));

#define MFMA32(a, b, c) __builtin_amdgcn_mfma_f32_32x32x16_bf16(a, b, c, 0, 0, 0)

// mfma_f32_32x32x16_bf16 layouts (cdna4_isa / m74,m101 verified C/D):
//   A[m][k]: m = lane&31, k = (lane>>5)*8 + j   (8 bf16 per lane, b128)
//   B[k][n]: n = lane&31, k = (lane>>5)*8 + j
//   C/D:     col = lane&31, row = (reg&3) + 8*(reg>>2) + 4*(lane>>5)
//
// FRAGMENT-MAJOR global layouts (a fragment load = base + lane*16B -> one
// coalesced 1KB transaction per wave):
//   Qf[(bh*16)+qt][wv][ks][lane][8] (Q rows,   QK^T B-operand)
//   Kf[bh][kt64][rh][ks][lane][8]   (K rows,   QK^T A-operand)
//   Vf[bh][kt64][dh][c ][lane][8]   (V^T rows, PV A-operand)
//   Af[(bh*16)+qt][wv][ks][lane][8] (attn out, proj A-operand)
//   Wpf[eb][cb][n][ks][lane][8]     (Wp,      proj B-operand)
//
// Register-direct fragment store (HW-verified in the attn Af epilogue,
// rounds 8/9): for a D-accumulator with col = lane&31 = outer-dim and
// regs = 8-groups of the fragment j-dim, per ks-chunk: cvt_pk 4 reg-pairs
// to bf16, permlane32_swap the h-halves, store one uint4 at lane*16B.

__device__ __forceinline__ unsigned cvt_pk_bf16(float lo, float hi) {
    unsigned r;
    asm("v_cvt_pk_bf16_f32 %0, %1, %2" : "=v"(r) : "v"(lo), "v"(hi));
    return r;
}

// pack regs rb..rb+7 of Og (scaled by s) -> one fragment uint4
__device__ __forceinline__ uint4 frag_pack(const f32x16& Og, int rb, float s) {
    unsigned a0 = cvt_pk_bf16(Og[rb + 0] * s, Og[rb + 1] * s);
    unsigned a1 = cvt_pk_bf16(Og[rb + 2] * s, Og[rb + 3] * s);
    unsigned b0 = cvt_pk_bf16(Og[rb + 4] * s, Og[rb + 5] * s);
    unsigned b1 = cvt_pk_bf16(Og[rb + 6] * s, Og[rb + 7] * s);
    asm("v_permlane32_swap_b32 %0, %1" : "+v"(a0), "+v"(b0));
    asm("v_permlane32_swap_b32 %0, %1" : "+v"(a1), "+v"(b1));
    uint4 pw; pw.x = a0; pw.y = a1; pw.z = b0; pw.w = b1;
    return pw;
}

// ---------------------------------------------------------------------------
// Kernel 1: QKV projection, bf16 MFMA, register-direct fragment epilogues.
// Block = (128-token tile, one head). ONE barrier; no LDS transposes.
//   q,k: acc = mfma(W, x) -> col = token, regs = e  -> Qf/Kf frag stores
//   v:   acc = mfma(x, W) -> col = e, regs = token  -> Vf frag stores
// q folded scale (1/sqrt(C))*log2(e). Optional Wp conversion epilogue.
// ---------------------------------------------------------------------------
__global__ __launch_bounds__(256) void qkv_kernel(
    const float* __restrict__ x,
    const float* __restrict__ Wq, const float* __restrict__ bq,
    const float* __restrict__ Wk, const float* __restrict__ bk,
    const float* __restrict__ Wv, const float* __restrict__ bv,
    __bf16* __restrict__ qf, __bf16* __restrict__ kf, __bf16* __restrict__ vf,
    const float* __restrict__ Wp, __bf16* __restrict__ wpf)
{
    __shared__ __bf16 Xs[128 * 72];          // x tile [t_local][d], bf16
    __shared__ __bf16 Ws[3][64 * 72];        // W[e][d], bf16

    const int tt  = blockIdx.x;               // 0..15 (128-token tile)
    const int bh  = blockIdx.y;               // 0..63
    const int b   = bh >> 4, h = bh & 15;
    const int t0  = tt * 128;
    const int tid = threadIdx.x;
    const int wave = tid >> 6, lane = tid & 63;
    const int m = lane & 31, hh = lane >> 5;

    // stage x (fp32 -> bf16): 128 rows x 64 cols = 2048 float4 chunks
    #pragma unroll
    for (int i = 0; i < 8; ++i) {
        const int idx = i * 256 + tid;
        const int r = idx >> 4, c = (idx & 15) * 4;
        const float4 x4 = *(const float4*)(x + ((size_t)(b * T_ + t0 + r)) * C_ + h * DH + c);
        const unsigned lo = ((unsigned)__builtin_bit_cast(unsigned short, (__bf16)x4.y) << 16)
                          | (unsigned)__builtin_bit_cast(unsigned short, (__bf16)x4.x);
        const unsigned hi = ((unsigned)__builtin_bit_cast(unsigned short, (__bf16)x4.w) << 16)
                          | (unsigned)__builtin_bit_cast(unsigned short, (__bf16)x4.z);
        *(unsigned*)&Xs[r * 72 + c]     = lo;
        *(unsigned*)&Xs[r * 72 + c + 2] = hi;
    }
    // stage weights (fp32 -> bf16): 3 x 1024 float4 chunks
    #pragma unroll
    for (int i = 0; i < 4; ++i) {
        const int idx = i * 256 + tid;
        const int r = idx >> 4, c = (idx & 15) * 4;
        const float* wsrc[3] = {Wq, Wk, Wv};
        #pragma unroll
        for (int wv_ = 0; wv_ < 3; ++wv_) {
            const float4 w4 = *(const float4*)(wsrc[wv_] + r * 64 + c);
            const unsigned lo = ((unsigned)__builtin_bit_cast(unsigned short, (__bf16)w4.y) << 16)
                              | (unsigned)__builtin_bit_cast(unsigned short, (__bf16)w4.x);
            const unsigned hi = ((unsigned)__builtin_bit_cast(unsigned short, (__bf16)w4.w) << 16)
                              | (unsigned)__builtin_bit_cast(unsigned short, (__bf16)w4.z);
            *(unsigned*)&Ws[wv_][r * 72 + c]     = lo;
            *(unsigned*)&Ws[wv_][r * 72 + c + 2] = hi;
        }
    }
    __syncthreads();   // the ONLY barrier

    // x fragments (dual-use: A-operand for v, B-operand for q/k -- identical
    // per-lane addressing)
    bf16x8 xf[4];
    #pragma unroll
    for (int ks = 0; ks < 4; ++ks)
        xf[ks] = *(const bf16x8*)&Xs[(wave * 32 + m) * 72 + ks * 16 + hh * 8];

    const float s32 = 0.03125f * 1.4426950408889634f;  // 1/sqrt(C) * log2(e)
    const int kt64l = wave >> 1, rh = wave & 1;        // wave's 64/32-row slot

    // ---- q and k: swapped operands, col = token, regs = e ----
    #pragma unroll
    for (int mat = 0; mat < 2; ++mat) {
        f32x16 acc0 = {}, acc1 = {};
        #pragma unroll
        for (int ks = 0; ks < 4; ++ks) {
            const bf16x8 w0 = *(const bf16x8*)&Ws[mat][(m) * 72 + ks * 16 + hh * 8];
            const bf16x8 w1 = *(const bf16x8*)&Ws[mat][(32 + m) * 72 + ks * 16 + hh * 8];
            acc0 = MFMA32(w0, xf[ks], acc0);   // e 0..31
            acc1 = MFMA32(w1, xf[ks], acc1);   // e 32..63
        }
        // bias over regs: e = (r&3) + 8*(r>>2) + 4*hh (+32 for acc1)
        const float* bias = (mat == 0) ? bq : bk;
        #pragma unroll
        for (int g = 0; g < 4; ++g) {
            const float4 bA = *(const float4*)(bias + 4 * hh + 8 * g);
            const float4 bB = *(const float4*)(bias + 32 + 4 * hh + 8 * g);
            acc0[4*g+0] += bA.x; acc0[4*g+1] += bA.y;
            acc0[4*g+2] += bA.z; acc0[4*g+3] += bA.w;
            acc1[4*g+0] += bB.x; acc1[4*g+1] += bB.y;
            acc1[4*g+2] += bB.z; acc1[4*g+3] += bB.w;
        }
        const float sc = (mat == 0) ? s32 : 1.0f;
        __bf16* base = (mat == 0)
            ? qf + ((size_t)(bh * 16 + tt)) * 8192 + wave * 2048 + lane * 8
            : kf + (((size_t)(bh * 32 + tt * 2 + kt64l) * 2 + rh) * 4) * 512 + lane * 8;
        #pragma unroll
        for (int ks = 0; ks < 4; ++ks) {
            const f32x16& Og = (ks < 2) ? acc0 : acc1;   // e-half
            *(uint4*)(base + ks * 512) = frag_pack(Og, (ks & 1) * 8, sc);
        }
    }

    // ---- v: original operands, col = e, regs = token ----
    {
        f32x16 acc0 = {}, acc1 = {};
        #pragma unroll
        for (int ks = 0; ks < 4; ++ks) {
            const bf16x8 w0 = *(const bf16x8*)&Ws[2][(m) * 72 + ks * 16 + hh * 8];
            const bf16x8 w1 = *(const bf16x8*)&Ws[2][(32 + m) * 72 + ks * 16 + hh * 8];
            acc0 = MFMA32(xf[ks], w0, acc0);   // e 0..31 (col = e = m)
            acc1 = MFMA32(xf[ks], w1, acc1);   // e 32..63
        }
        const float b0v = bv[m], b1v = bv[32 + m];
        #pragma unroll
        for (int r = 0; r < 16; ++r) { acc0[r] += b0v; acc1[r] += b1v; }
        __bf16* vbase = vf + (((size_t)(bh * 32 + tt * 2 + kt64l) * 2) * 4) * 512 + lane * 8;
        #pragma unroll
        for (int dh = 0; dh < 2; ++dh) {
            const f32x16& Og = dh ? acc1 : acc0;
            #pragma unroll
            for (int cl = 0; cl < 2; ++cl)     // token 16-group within wave
                *(uint4*)(vbase + dh * 2048 + (rh * 2 + cl) * 512)
                    = frag_pack(Og, cl * 8, 1.0f);
        }
    }

    // optional Wp fragment-major conversion: 128 chunks per block (tid<128)
    if (wpf != nullptr && tid < 128) {
        const int ci = (bh * 16 + tt) * 128 + tid;     // chunk 0..131071
        const int ln = ci & 63;
        const int ks = (ci >> 6) & 3;
        const int n  = (ci >> 8) & 3;
        const int cb = (ci >> 10) & 15;
        const int eb = ci >> 14;
        const int row = eb * 128 + n * 32 + (ln & 31);
        const int col = cb * 64 + ks * 16 + (ln >> 5) * 8;
        const float4 w0 = *(const float4*)(Wp + (size_t)row * C_ + col);
        const float4 w1 = *(const float4*)(Wp + (size_t)row * C_ + col + 4);
        uint4 p;
        p.x = ((unsigned)__builtin_bit_cast(unsigned short, (__bf16)w0.y) << 16)
            |  (unsigned)__builtin_bit_cast(unsigned short, (__bf16)w0.x);
        p.y = ((unsigned)__builtin_bit_cast(unsigned short, (__bf16)w0.w) << 16)
            |  (unsigned)__builtin_bit_cast(unsigned short, (__bf16)w0.z);
        p.z = ((unsigned)__builtin_bit_cast(unsigned short, (__bf16)w1.y) << 16)
            |  (unsigned)__builtin_bit_cast(unsigned short, (__bf16)w1.x);
        p.w = ((unsigned)__builtin_bit_cast(unsigned short, (__bf16)w1.w) << 16)
            |  (unsigned)__builtin_bit_cast(unsigned short, (__bf16)w1.z);
        *(uint4*)(wpf + (size_t)ci * 8) = p;
    }
}

// ---------------------------------------------------------------------------
// Kernel 2: flash attention (round-9 control; only change: Q now read from
// fragment-major Qf -> the one-time Q load is coalesced too).
// ---------------------------------------------------------------------------
__global__ __launch_bounds__(256, 2) void attn_kernel(
    const __bf16* __restrict__ qf, const __bf16* __restrict__ kf,
    const __bf16* __restrict__ vf, __bf16* __restrict__ af)
{
    const int bh  = blockIdx.x;         // XCD-locality axis (id%8 == bh%8)
    const int q0  = blockIdx.y * 256;   // 256-row block tile
    const int tid = threadIdx.x;
    const int wave = tid >> 6, lane = tid & 63;
    const int m = lane & 31, h = lane >> 5;
    const int row0 = q0 + wave * 64;    // this wave's 64-row slice

    const __bf16* kfb = kf + (size_t)bh * (T_ * DH);   // [kt64][rh][ks][lane][8]
    const __bf16* vfb = vf + (size_t)bh * (T_ * DH);   // [kt64][dh][c ][lane][8]

    // Q fragments from Qf (coalesced lane*16B)
    const __bf16* qbase = qf + ((size_t)(bh * 16 + (row0 >> 7))) * 8192
                             + ((row0 >> 5) & 3) * 2048 + lane * 8;
    bf16x8 qfa[4], qfb_[4];
    #pragma unroll
    for (int ks = 0; ks < 4; ++ks) {
        qfa[ks]  = *(const bf16x8*)(qbase + ks * 512);
        qfb_[ks] = *(const bf16x8*)(qbase + 2048 + ks * 512);
    }

    f32x16 Oa0 = {}, Oa1 = {}, Ob0 = {}, Ob1 = {};   // O^T per half [d-half][q]
    float lsa = 0.f, lsb = 0.f;

    for (int kt = 0; kt < 32; ++kt) {
        const __bf16* kt_k = kfb + kt * 4096;
        const __bf16* kt_v = vfb + kt * 4096;
        #pragma unroll
        for (int rh = 0; rh < 2; ++rh) {
            bf16x8 kfr[4];
            #pragma unroll
            for (int ks = 0; ks < 4; ++ks)
                kfr[ks] = *(const bf16x8*)(kt_k + rh * 2048 + ks * 512 + lane * 8);
            // shared K fragments -> S for BOTH q-halves (2 MFMA per load)
            f32x16 Sa = {}, Sb = {};
            #pragma unroll
            for (int ks = 0; ks < 4; ++ks) {
                Sa = MFMA32(kfr[ks], qfa[ks],  Sa);
                Sb = MFMA32(kfr[ks], qfb_[ks], Sb);
            }

            #pragma unroll
            for (int cc = 0; cc < 2; ++cc) {
                const int rb = cc * 8;
                // half a softmax chunk
                float a0f = __builtin_amdgcn_exp2f(Sa[rb + 0]);
                float a1f = __builtin_amdgcn_exp2f(Sa[rb + 1]);
                float a2f = __builtin_amdgcn_exp2f(Sa[rb + 2]);
                float a3f = __builtin_amdgcn_exp2f(Sa[rb + 3]);
                float a4f = __builtin_amdgcn_exp2f(Sa[rb + 4]);
                float a5f = __builtin_amdgcn_exp2f(Sa[rb + 5]);
                float a6f = __builtin_amdgcn_exp2f(Sa[rb + 6]);
                float a7f = __builtin_amdgcn_exp2f(Sa[rb + 7]);
                lsa += ((a0f + a1f) + (a2f + a3f)) + ((a4f + a5f) + (a6f + a7f));
                unsigned pa0 = cvt_pk_bf16(a0f, a1f);
                unsigned pa1 = cvt_pk_bf16(a2f, a3f);
                unsigned pa2 = cvt_pk_bf16(a4f, a5f);
                unsigned pa3 = cvt_pk_bf16(a6f, a7f);
                asm("v_permlane32_swap_b32 %0, %1" : "+v"(pa0), "+v"(pa2));
                asm("v_permlane32_swap_b32 %0, %1" : "+v"(pa1), "+v"(pa3));
                const uint4 pwa = {pa0, pa1, pa2, pa3};
                const bf16x8 pba = __builtin_bit_cast(bf16x8, pwa);
                // half b softmax chunk
                float b0f = __builtin_amdgcn_exp2f(Sb[rb + 0]);
                float b1f = __builtin_amdgcn_exp2f(Sb[rb + 1]);
                float b2f = __builtin_amdgcn_exp2f(Sb[rb + 2]);
                float b3f = __builtin_amdgcn_exp2f(Sb[rb + 3]);
                float b4f = __builtin_amdgcn_exp2f(Sb[rb + 4]);
                float b5f = __builtin_amdgcn_exp2f(Sb[rb + 5]);
                float b6f = __builtin_amdgcn_exp2f(Sb[rb + 6]);
                float b7f = __builtin_amdgcn_exp2f(Sb[rb + 7]);
                lsb += ((b0f + b1f) + (b2f + b3f)) + ((b4f + b5f) + (b6f + b7f));
                unsigned pb0 = cvt_pk_bf16(b0f, b1f);
                unsigned pb1 = cvt_pk_bf16(b2f, b3f);
                unsigned pb2 = cvt_pk_bf16(b4f, b5f);
                unsigned pb3 = cvt_pk_bf16(b6f, b7f);
                asm("v_permlane32_swap_b32 %0, %1" : "+v"(pb0), "+v"(pb2));
                asm("v_permlane32_swap_b32 %0, %1" : "+v"(pb1), "+v"(pb3));
                const uint4 pwb = {pb0, pb1, pb2, pb3};
                const bf16x8 pbb = __builtin_bit_cast(bf16x8, pwb);

                // shared V fragments -> PV for both halves (2 MFMA per load)
                const int c = rh * 2 + cc;          // kv 16-slot
                const bf16x8 v0 = *(const bf16x8*)(kt_v + c * 512 + lane * 8);
                const bf16x8 v1 = *(const bf16x8*)(kt_v + 2048 + c * 512 + lane * 8);
                Oa0 = MFMA32(v0, pba, Oa0);
                Oa1 = MFMA32(v1, pba, Oa1);
                Ob0 = MFMA32(v0, pbb, Ob0);
                Ob1 = MFMA32(v1, pbb, Ob1);
            }
        }
    }

    // l reduction: lanes l, l+32 hold complementary kv rows of the same q
    lsa += __shfl_xor(lsa, 32);
    lsb += __shfl_xor(lsb, 32);
    const float linva = 1.0f / lsa, linvb = 1.0f / lsb;

    // register-direct Af fragment stores, per half
    const int qt = row0 >> 7;                 // 128-row tile index
    const int wv_a = (row0 >> 5) & 3;         // 32-row slice within tile
    __bf16* ab_a = af + ((size_t)(bh * 16 + qt)) * 8192 + wv_a * 2048 + lane * 8;
    __bf16* ab_b = ab_a + 2048;               // half b is the next 32-row slice
    #pragma unroll
    for (int ks = 0; ks < 4; ++ks) {
        *(uint4*)(ab_a + ks * 512) = frag_pack((ks < 2) ? Oa0 : Oa1, (ks & 1) * 8, linva);
        *(uint4*)(ab_b + ks * 512) = frag_pack((ks < 2) ? Ob0 : Ob1, (ks & 1) * 8, linvb);
    }
}

// ---------------------------------------------------------------------------
// Kernel 2.5 (FALLBACK ONLY, when workspace < 66 MiB): standalone Wp
// fragment-major conversion.
// ---------------------------------------------------------------------------
__global__ __launch_bounds__(256) void wpconv_kernel(
    const float* __restrict__ Wp, __bf16* __restrict__ wpf)
{
    const int ci = blockIdx.x * 256 + threadIdx.x;     // chunk 0..131071
    const int ln = ci & 63;
    const int ks = (ci >> 6) & 3;
    const int n  = (ci >> 8) & 3;
    const int cb = (ci >> 10) & 15;
    const int eb = ci >> 14;
    const int row = eb * 128 + n * 32 + (ln & 31);
    const int col = cb * 64 + ks * 16 + (ln >> 5) * 8;
    const float4 w0 = *(const float4*)(Wp + (size_t)row * C_ + col);
    const float4 w1 = *(const float4*)(Wp + (size_t)row * C_ + col + 4);
    uint4 p;
    p.x = ((unsigned)__builtin_bit_cast(unsigned short, (__bf16)w0.y) << 16)
        |  (unsigned)__builtin_bit_cast(unsigned short, (__bf16)w0.x);
    p.y = ((unsigned)__builtin_bit_cast(unsigned short, (__bf16)w0.w) << 16)
        |  (unsigned)__builtin_bit_cast(unsigned short, (__bf16)w0.z);
    p.z = ((unsigned)__builtin_bit_cast(unsigned short, (__bf16)w1.y) << 16)
        |  (unsigned)__builtin_bit_cast(unsigned short, (__bf16)w1.x);
    p.w = ((unsigned)__builtin_bit_cast(unsigned short, (__bf16)w1.w) << 16)
        |  (unsigned)__builtin_bit_cast(unsigned short, (__bf16)w1.z);
    *(uint4*)(wpf + (size_t)ci * 8) = p;
}

// ---------------------------------------------------------------------------
// Kernel 3: output projection, LDS/barrier-free, load:MFMA = 0.75.
// Wave = 64 tok x 128 e (8 acc tiles); block = 256 tok x 128 e;
// grid (32, 8) = 256 blocks = 1/CU. Per cb: 8 af + 16 wpf coalesced loads
// feed 32 MFMA (was 12 loads / 8 MFMA = 1.5). af shared by the 8 eb-blocks
// of one XCD (id%8 = tb%8); wpf (2 MiB) L2-resident everywhere.
// ---------------------------------------------------------------------------
__global__ __launch_bounds__(256) void proj_kernel(
    const __bf16* __restrict__ af,     // Af fragment-major
    const __bf16* __restrict__ wpf,    // Wpf fragment-major
    const float* __restrict__ bp,
    float* __restrict__ out)
{
    const int tb = blockIdx.x, eb = blockIdx.y;   // tb: 256-token tiles
    const int tid = threadIdx.x;
    const int wave = tid >> 6, lane = tid & 63;
    const int m = lane & 31, h = lane >> 5;
    const int b = tb >> 3;
    const int qt = (tb & 7) * 2 + (wave >> 1);    // local 128-tile 0..15
    const int wv0 = (wave & 1) * 2;               // first 32-row slice
    const int e0 = eb * 128;

    const __bf16* abase = af + ((size_t)(b * 256 + qt)) * 8192
                             + wv0 * 2048 + lane * 8;
    const __bf16* wbase = wpf + (size_t)eb * 131072 + lane * 8;

    f32x16 acc[2][4] = {};   // [tok-32-slice u][e-32-tile n] (all idx unrolled)

    for (int cb = 0; cb < 16; ++cb) {
        const __bf16* ap = abase + (size_t)cb * 131072;   // 16 qtiles * 8192
        const __bf16* wp = wbase + (size_t)cb * 8192;
        bf16x8 a0[4], a1[4];
        #pragma unroll
        for (int ks = 0; ks < 4; ++ks) {
            a0[ks] = *(const bf16x8*)(ap + ks * 512);
            a1[ks] = *(const bf16x8*)(ap + 2048 + ks * 512);
        }
        #pragma unroll
        for (int n = 0; n < 4; ++n) {
            #pragma unroll
            for (int ks = 0; ks < 4; ++ks) {
                const bf16x8 bf = *(const bf16x8*)(wp + (n * 4 + ks) * 512);
                acc[0][n] = MFMA32(a0[ks], bf, acc[0][n]);
                acc[1][n] = MFMA32(a1[ks], bf, acc[1][n]);
            }
        }
    }

    const int tokb = b * T_ + qt * 128;
    #pragma unroll
    for (int n = 0; n < 4; ++n) {
        const int e = e0 + n * 32 + m;
        const float bias = bp[e];
        #pragma unroll
        for (int u = 0; u < 2; ++u) {
            const int t0 = tokb + (wv0 + u) * 32;
            #pragma unroll
            for (int r = 0; r < 16; ++r) {
                const int R = (r & 3) + 8 * (r >> 2) + 4 * h;
                out[(size_t)(t0 + R) * C_ + e] = acc[u][n][r] + bias;
            }
        }
    }
}

// ---------------------------------------------------------------------------
// Workspace (bf16): qf | kf | vf | af, each B*H*T*DH = 8388608 elems = 64 MiB.
// Roomy path (ws >= 66 MiB): wpf at d_ws + 4N, converted inside qkv ->
// 3 kernels. Fallback: wpf aliases qf (dead after attn), standalone wpconv.
// ---------------------------------------------------------------------------
extern "C" void kernel_launch(void* const* d_in, const int* in_sizes, int n_in,
                              void* d_out, int out_size, void* d_ws, size_t ws_size,
                              hipStream_t stream)
{
    const float* x  = (const float*)d_in[0];
    const float* Wq = (const float*)d_in[1];
    const float* bq = (const float*)d_in[2];
    const float* Wk = (const float*)d_in[3];
    const float* bk = (const float*)d_in[4];
    const float* Wv = (const float*)d_in[5];
    const float* bv = (const float*)d_in[6];
    const float* Wp = (const float*)d_in[7];
    const float* bp = (const float*)d_in[8];

    const size_t N = (size_t)BH * T_ * DH;
    __bf16* qws  = (__bf16*)d_ws;
    __bf16* kws  = qws + N;
    __bf16* vtws = kws + N;
    __bf16* aws  = vtws + N;

    const size_t need = 4 * N * sizeof(__bf16) + (size_t)C_ * C_ * sizeof(__bf16);
    const bool roomy = ws_size >= need;
    __bf16* wpf = roomy ? (aws + N) : qws;    // fallback: qf dead after attn

    qkv_kernel<<<dim3(16, 64), 256, 0, stream>>>(
        x, Wq, bq, Wk, bk, Wv, bv, qws, kws, vtws,
        Wp, roomy ? wpf : nullptr);
    attn_kernel<<<dim3(64, 8), 256, 0, stream>>>(qws, kws, vtws, aws);
    if (!roomy)
        wpconv_kernel<<<dim3(512), 256, 0, stream>>>(Wp, wpf);
    proj_kernel<<<dim3(32, 8), 256, 0, stream>>>(aws, wpf, bp, (float*)d_out);
}

// Round 13
// 214.041 us; speedup vs baseline: 1.0784x; 1.0382x over previous
//
#include <hip/hip_runtime.h>
#include <hip/hip_bf16.h>
#include <cstddef>

// Problem constants (SelfAttention: B=4, T=2048, H=16, Dh=64, C=1024)
#define B_  4
#define T_  2048
#define H_  16
#define DH  64
#define C_  1024
#define BH  64    // B_*H_

typedef float  f32x16 __attribute__((ext_vector_type(16)));
typedef __bf16 bf16x8 __attribute__((ext_vector_type(8)));
typedef __bf16 bf16x4 __attribute__((ext_vector_type(4)));

#define MFMA32(a, b, c) __builtin_amdgcn_mfma_f32_32x32x16_bf16(a, b, c, 0, 0, 0)

// mfma_f32_32x32x16_bf16 layouts (cdna4_isa / m74,m101 verified C/D):
//   A[m][k]: m = lane&31, k = (lane>>5)*8 + j   (8 bf16 per lane, b128)
//   B[k][n]: n = lane&31, k = (lane>>5)*8 + j
//   C/D:     col = lane&31, row = (reg&3) + 8*(reg>>2) + 4*(lane>>5)
//
// K/V are stored FRAGMENT-MAJOR in global:
//   Kf[bh][kt64][rh][ks][lane][8]  (elem = K[kt64*64+rh*32+(lane&31)][ks*16+(lane>>5)*8+j])
//   Vf[bh][kt64][dh][c ][lane][8]  (elem = V^T[dh*32+(lane&31)][kt64*64+c*16+(lane>>5)*8+j])
// so an attention fragment load is base + lane*16B: ONE coalesced 1KB
// transaction (fixes the 32-way segmentation of direct [t][d] loads).
//
// NOTE (session ledger): this file is the round-5-measured ensemble
// (216.0 us total; attn 91.1 / tail 124.9). Seven subsequent tail
// restructures (rounds 6-12: weight preconversion, LDS-free proj,
// split-kv, 64-row waves, register-direct qkv epilogues, kernel fusion)
// all measured 222-260 total with attn invariant at 89-92 -> reverted
// to the measured optimum.

__device__ __forceinline__ unsigned cvt_pk_bf16(float lo, float hi) {
    unsigned r;
    asm("v_cvt_pk_bf16_f32 %0, %1, %2" : "=v"(r) : "v"(lo), "v"(hi));
    return r;
}

// ---------------------------------------------------------------------------
// Kernel 1: QKV projection, bf16 MFMA. Block = (128-token tile, one head).
// q written [bh][t][d] with (1/sqrt(C))*log2(e) folded (attention uses exp2).
// k and v written fragment-major (see above) via LDS transposes.
// ---------------------------------------------------------------------------
__global__ __launch_bounds__(256) void qkv_kernel(
    const float* __restrict__ x,
    const float* __restrict__ Wq, const float* __restrict__ bq,
    const float* __restrict__ Wk, const float* __restrict__ bk,
    const float* __restrict__ Wv, const float* __restrict__ bv,
    __bf16* __restrict__ q, __bf16* __restrict__ kf, __bf16* __restrict__ vf)
{
    __shared__ __bf16 Xs[128 * 72];          // x tile [t_local][d], bf16
    __shared__ __bf16 Ws[3][64 * 72];        // W[e][d], bf16
    __bf16* Vtl = Xs;                         // alias: V^T [e][t_local], stride 136
    __bf16* Kst = &Ws[0][0];                  // alias after mat loop: K [t_local][d], stride 72

    const int tt  = blockIdx.x;               // 0..15 (128-token tile)
    const int bh  = blockIdx.y;               // 0..63
    const int b   = bh >> 4, h = bh & 15;
    const int t0  = tt * 128;
    const int tid = threadIdx.x;
    const int wave = tid >> 6, lane = tid & 63;
    const int m = lane & 31, hh = lane >> 5;

    // stage x (fp32 -> bf16): 128 rows x 64 cols = 2048 float4 chunks
    #pragma unroll
    for (int i = 0; i < 8; ++i) {
        const int idx = i * 256 + tid;
        const int r = idx >> 4, c = (idx & 15) * 4;
        const float4 x4 = *(const float4*)(x + ((size_t)(b * T_ + t0 + r)) * C_ + h * DH + c);
        const unsigned lo = ((unsigned)__builtin_bit_cast(unsigned short, (__bf16)x4.y) << 16)
                          | (unsigned)__builtin_bit_cast(unsigned short, (__bf16)x4.x);
        const unsigned hi = ((unsigned)__builtin_bit_cast(unsigned short, (__bf16)x4.w) << 16)
                          | (unsigned)__builtin_bit_cast(unsigned short, (__bf16)x4.z);
        *(unsigned*)&Xs[r * 72 + c]     = lo;
        *(unsigned*)&Xs[r * 72 + c + 2] = hi;
    }
    // stage weights (fp32 -> bf16): 3 x 1024 float4 chunks
    #pragma unroll
    for (int i = 0; i < 4; ++i) {
        const int idx = i * 256 + tid;
        const int r = idx >> 4, c = (idx & 15) * 4;
        const float* wsrc[3] = {Wq, Wk, Wv};
        #pragma unroll
        for (int wv_ = 0; wv_ < 3; ++wv_) {
            const float4 w4 = *(const float4*)(wsrc[wv_] + r * 64 + c);
            const unsigned lo = ((unsigned)__builtin_bit_cast(unsigned short, (__bf16)w4.y) << 16)
                              | (unsigned)__builtin_bit_cast(unsigned short, (__bf16)w4.x);
            const unsigned hi = ((unsigned)__builtin_bit_cast(unsigned short, (__bf16)w4.w) << 16)
                              | (unsigned)__builtin_bit_cast(unsigned short, (__bf16)w4.z);
            *(unsigned*)&Ws[wv_][r * 72 + c]     = lo;
            *(unsigned*)&Ws[wv_][r * 72 + c + 2] = hi;
        }
    }
    __syncthreads();

    // hoist x A-fragments (wave-private rows 32*wave + m)
    bf16x8 xf[4];
    #pragma unroll
    for (int ks = 0; ks < 4; ++ks)
        xf[ks] = *(const bf16x8*)&Xs[(wave * 32 + m) * 72 + ks * 16 + hh * 8];
    __syncthreads();   // all frag reads done before Vtl aliases Xs

    // 1/sqrt(1024) * log2(e) folded into q (attention uses exp2 directly)
    const float s32 = 0.03125f * 1.4426950408889634f;

    unsigned kpk[16];   // packed k results, staged to LDS after the mat loop

    #pragma unroll
    for (int mat = 0; mat < 3; ++mat) {
        f32x16 acc0 = {}, acc1 = {};
        #pragma unroll
        for (int ks = 0; ks < 4; ++ks) {
            const bf16x8 w0 = *(const bf16x8*)&Ws[mat][(m) * 72 + ks * 16 + hh * 8];
            const bf16x8 w1 = *(const bf16x8*)&Ws[mat][(32 + m) * 72 + ks * 16 + hh * 8];
            acc0 = MFMA32(xf[ks], w0, acc0);
            acc1 = MFMA32(xf[ks], w1, acc1);
        }
        const float* bias = (mat == 0) ? bq : (mat == 1) ? bk : bv;
        const float b0 = bias[m], b1 = bias[32 + m];
        #pragma unroll
        for (int r = 0; r < 16; ++r) {
            const int R = (r & 3) + 8 * (r >> 2) + 4 * hh;   // token row in tile
            const int tloc = wave * 32 + R;
            const float v0 = acc0[r] + b0, v1 = acc1[r] + b1;
            if (mat == 0) {
                const size_t base = ((size_t)bh * T_ + t0 + tloc) * DH;
                q[base + m]      = (__bf16)(v0 * s32);
                q[base + 32 + m] = (__bf16)(v1 * s32);
            } else if (mat == 1) {
                kpk[r] = ((unsigned)__builtin_bit_cast(unsigned short, (__bf16)v1) << 16)
                       |  (unsigned)__builtin_bit_cast(unsigned short, (__bf16)v0);
            } else {
                Vtl[(m) * 136 + tloc]      = (__bf16)v0;   // V^T [e][t_local]
                Vtl[(32 + m) * 136 + tloc] = (__bf16)v1;
            }
        }
    }
    __syncthreads();   // Ws reads done (mat loop), Vtl complete

    // stage k tile [t_local][d] into Kst (Ws area, now dead)
    #pragma unroll
    for (int r = 0; r < 16; ++r) {
        const int R = (r & 3) + 8 * (r >> 2) + 4 * hh;
        const int tloc = wave * 32 + R;
        Kst[tloc * 72 + m]      = __builtin_bit_cast(__bf16, (unsigned short)(kpk[r] & 0xffff));
        Kst[tloc * 72 + 32 + m] = __builtin_bit_cast(__bf16, (unsigned short)(kpk[r] >> 16));
    }

    // Vf fragment-major out (reads Vtl; no barrier needed vs Kst region)
    #pragma unroll
    for (int i = 0; i < 4; ++i) {
        const int idx = i * 256 + tid;
        const int ln = idx & 63, c_ = idx >> 6;           // c_ 0..15
        const int kt64l = c_ >> 3, dh = (c_ >> 2) & 1, cN = c_ & 3;
        const __bf16* src = &Vtl[(dh * 32 + (ln & 31)) * 136 + kt64l * 64 + cN * 16 + (ln >> 5) * 8];
        __bf16* dst = vf + ((((size_t)(bh * 32 + tt * 2 + kt64l) * 2 + dh) * 4 + cN) * 64 + ln) * 8;
        *(uint4*)dst = *(const uint4*)src;
    }
    __syncthreads();   // Kst visible

    // Kf fragment-major out (reads Kst)
    #pragma unroll
    for (int i = 0; i < 4; ++i) {
        const int idx = i * 256 + tid;
        const int ln = idx & 63, c_ = idx >> 6;
        const int kt64l = c_ >> 3, rh = (c_ >> 2) & 1, ks = c_ & 3;
        const __bf16* src = &Kst[(kt64l * 64 + rh * 32 + (ln & 31)) * 72 + ks * 16 + (ln >> 5) * 8];
        __bf16* dst = kf + ((((size_t)(bh * 32 + tt * 2 + kt64l) * 2 + rh) * 4 + ks) * 64 + ln) * 8;
        *(uint4*)dst = *(const uint4*)src;
    }
}

// ---------------------------------------------------------------------------
// Kernel 2: flash attention. Swapped-operand in-register softmax; K/V read
// fragment-major from global (coalesced 1KB loads, L2-resident via bh-on-x
// XCD mapping) -- NO LDS / NO barriers in the main loop.
// Grid (64 bh, 16 q-tiles) = 1024 blocks = 4 blocks/CU; 128-row q-tile,
// 4 waves x 32 q-rows. LDS only for the output transpose (18.4 KB).
// ---------------------------------------------------------------------------
__global__ __launch_bounds__(256, 4) void attn_kernel(
    const __bf16* __restrict__ q, const __bf16* __restrict__ kf,
    const __bf16* __restrict__ vf, __bf16* __restrict__ o)
{
    __shared__ __bf16 Os[128 * 72];          // epilogue transpose buffer

    const int bh  = blockIdx.x;              // XCD-locality axis (id%8 == bh%8)
    const int q0  = blockIdx.y * 128;
    const int tid = threadIdx.x;
    const int wave = tid >> 6, lane = tid & 63;
    const int m = lane & 31, h = lane >> 5;

    const __bf16* qb  = q  + (size_t)bh * T_ * DH;
    const __bf16* kfb = kf + (size_t)bh * (T_ * DH);   // [kt64][rh][ks][lane][8]
    const __bf16* vfb = vf + (size_t)bh * (T_ * DH);   // [kt64][dh][c ][lane][8]

    // Q fragments (one-time; [t][d] layout, segmented but negligible)
    bf16x8 qf[4];
    #pragma unroll
    for (int ks = 0; ks < 4; ++ks)
        qf[ks] = *(const bf16x8*)(qb + (size_t)(q0 + wave * 32 + m) * DH + ks * 16 + h * 8);

    f32x16 O0 = {}, O1 = {};                 // O^T [d 0..31 | 32..63][q]
    float lsum = 0.f;

    for (int kt = 0; kt < 32; ++kt) {
        const __bf16* kt_k = kfb + kt * 4096;
        const __bf16* kt_v = vfb + kt * 4096;
        #pragma unroll
        for (int rh = 0; rh < 2; ++rh) {
            bf16x8 kfr[4];
            #pragma unroll
            for (int ks = 0; ks < 4; ++ks)
                kfr[ks] = *(const bf16x8*)(kt_k + rh * 2048 + ks * 512 + lane * 8);
            f32x16 S = {};
            #pragma unroll
            for (int ks = 0; ks < 4; ++ks)
                S = MFMA32(kfr[ks], qf[ks], S);

            #pragma unroll
            for (int cc = 0; cc < 2; ++cc) {
                const int rb = cc * 8;
                float e0 = __builtin_amdgcn_exp2f(S[rb + 0]);
                float e1 = __builtin_amdgcn_exp2f(S[rb + 1]);
                float e2 = __builtin_amdgcn_exp2f(S[rb + 2]);
                float e3 = __builtin_amdgcn_exp2f(S[rb + 3]);
                float e4 = __builtin_amdgcn_exp2f(S[rb + 4]);
                float e5 = __builtin_amdgcn_exp2f(S[rb + 5]);
                float e6 = __builtin_amdgcn_exp2f(S[rb + 6]);
                float e7 = __builtin_amdgcn_exp2f(S[rb + 7]);
                lsum += ((e0 + e1) + (e2 + e3)) + ((e4 + e5) + (e6 + e7));
                unsigned a0 = cvt_pk_bf16(e0, e1);
                unsigned a1 = cvt_pk_bf16(e2, e3);
                unsigned b0 = cvt_pk_bf16(e4, e5);
                unsigned b1 = cvt_pk_bf16(e6, e7);
                asm("v_permlane32_swap_b32 %0, %1" : "+v"(a0), "+v"(b0));
                asm("v_permlane32_swap_b32 %0, %1" : "+v"(a1), "+v"(b1));
                const uint4 pw = {a0, a1, b0, b1};
                const bf16x8 pb = __builtin_bit_cast(bf16x8, pw);
                const int c = rh * 2 + cc;          // kv 16-slot
                const bf16x8 v0 = *(const bf16x8*)(kt_v + c * 512 + lane * 8);
                const bf16x8 v1 = *(const bf16x8*)(kt_v + 2048 + c * 512 + lane * 8);
                O0 = MFMA32(v0, pb, O0);
                O1 = MFMA32(v1, pb, O1);
            }
        }
    }

    // l[q]: lanes l and l+32 hold complementary kv halves of the same q-row
    lsum += __shfl_xor(lsum, 32);
    const float linv = 1.0f / lsum;

    // O^T -> LDS: lane owns q-row (wave*32 + m); reg r -> d = (r&3)+8*(r>>2)+4h
    #pragma unroll
    for (int g = 0; g < 4; ++g) {
        bf16x4 w0, w1;
        #pragma unroll
        for (int j = 0; j < 4; ++j) {
            w0[j] = (__bf16)(O0[4 * g + j] * linv);
            w1[j] = (__bf16)(O1[4 * g + j] * linv);
        }
        const int row = (wave * 32 + m) * 72;
        *(bf16x4*)&Os[row + 8 * g + 4 * h]      = w0;
        *(bf16x4*)&Os[row + 32 + 8 * g + 4 * h] = w1;
    }
    __syncthreads();

    // fully coalesced store: 128 rows x 64 bf16 = 1024 uint4 / 256 threads
    __bf16* ob = o + ((size_t)bh * T_ + q0) * DH;
    #pragma unroll
    for (int i = 0; i < 4; ++i) {
        const int idx = i * 256 + tid;
        const int r = idx >> 3, c = (idx & 7) * 8;
        *(uint4*)(ob + (size_t)r * DH + c) = *(uint4*)&Os[r * 72 + c];
    }
}

// ---------------------------------------------------------------------------
// Kernel 2.5: Wp fp32 -> bf16 pre-conversion (once; into dead q region).
// ---------------------------------------------------------------------------
__global__ __launch_bounds__(256) void wpconv_kernel(
    const float* __restrict__ Wp, __bf16* __restrict__ Wpb)
{
    const size_t idx = (size_t)(blockIdx.x * 256 + threadIdx.x) * 4;
    const float4 w4 = *(const float4*)(Wp + idx);
    const unsigned lo = ((unsigned)__builtin_bit_cast(unsigned short, (__bf16)w4.y) << 16)
                      | (unsigned)__builtin_bit_cast(unsigned short, (__bf16)w4.x);
    const unsigned hi = ((unsigned)__builtin_bit_cast(unsigned short, (__bf16)w4.w) << 16)
                      | (unsigned)__builtin_bit_cast(unsigned short, (__bf16)w4.z);
    uint2 p; p.x = lo; p.y = hi;
    *(uint2*)(Wpb + idx) = p;
}

// ---------------------------------------------------------------------------
// Kernel 3: output projection, bf16 MFMA. out[tok][e] = A[tok][:].Wpb[e][:]+bp
// Block = 128 tokens x 128 e-cols; K-chunks of 64 (== one head of A).
// B operand pre-converted bf16 (16B copies, no cvt).
// ---------------------------------------------------------------------------
__global__ __launch_bounds__(256) void proj_kernel(
    const __bf16* __restrict__ a,      // [bh][t][d]
    const __bf16* __restrict__ Wpb, const float* __restrict__ bp,
    float* __restrict__ out)
{
    __shared__ __bf16 As[128 * 72];
    __shared__ __bf16 Bs[128 * 72];

    const int tb = blockIdx.x, eb = blockIdx.y;
    const int tid = threadIdx.x;
    const int wave = tid >> 6, lane = tid & 63;
    const int m = lane & 31, h = lane >> 5;
    const int tok0 = tb * 128;
    const int b = tok0 >> 11, t0 = tok0 & (T_ - 1);
    const int e0 = eb * 128;

    f32x16 acc[4] = {f32x16{}, f32x16{}, f32x16{}, f32x16{}};

    for (int cb = 0; cb < 16; ++cb) {
        __syncthreads();
        // As: 128 rows x 64 bf16 (head cb of A), direct bf16 copy
        #pragma unroll
        for (int i = 0; i < 4; ++i) {
            const int idx = i * 256 + tid;
            const int r = idx >> 3, c = (idx & 7) * 8;
            *(uint4*)&As[r * 72 + c] =
                *(const uint4*)(a + ((size_t)(b * H_ + cb) * T_ + t0 + r) * DH + c);
        }
        // Bs: Wpb rows e0+r, cols cb*64.., direct bf16 copy
        #pragma unroll
        for (int i = 0; i < 4; ++i) {
            const int idx = i * 256 + tid;
            const int r = idx >> 3, c = (idx & 7) * 8;
            *(uint4*)&Bs[r * 72 + c] =
                *(const uint4*)(Wpb + (size_t)(e0 + r) * C_ + cb * 64 + c);
        }
        __syncthreads();

        #pragma unroll
        for (int ks = 0; ks < 4; ++ks) {
            const bf16x8 af = *(const bf16x8*)&As[(wave * 32 + m) * 72 + ks * 16 + h * 8];
            #pragma unroll
            for (int n = 0; n < 4; ++n) {
                const bf16x8 bf = *(const bf16x8*)&Bs[(n * 32 + m) * 72 + ks * 16 + h * 8];
                acc[n] = MFMA32(af, bf, acc[n]);
            }
        }
    }

    #pragma unroll
    for (int n = 0; n < 4; ++n) {
        const int e = e0 + n * 32 + m;
        const float bias = bp[e];
        #pragma unroll
        for (int r = 0; r < 16; ++r) {
            const int R = (r & 3) + 8 * (r >> 2) + 4 * h;
            out[(size_t)(tok0 + wave * 32 + R) * C_ + e] = acc[n][r] + bias;
        }
    }
}

// ---------------------------------------------------------------------------
// Workspace (bf16): q | kf | vf | attn_out, each B*H*T*DH = 8388608 elems
// -> 64 MiB total. Wpb (2 MiB) reuses the q region (dead after attn).
// ---------------------------------------------------------------------------
extern "C" void kernel_launch(void* const* d_in, const int* in_sizes, int n_in,
                              void* d_out, int out_size, void* d_ws, size_t ws_size,
                              hipStream_t stream)
{
    const float* x  = (const float*)d_in[0];
    const float* Wq = (const float*)d_in[1];
    const float* bq = (const float*)d_in[2];
    const float* Wk = (const float*)d_in[3];
    const float* bk = (const float*)d_in[4];
    const float* Wv = (const float*)d_in[5];
    const float* bv = (const float*)d_in[6];
    const float* Wp = (const float*)d_in[7];
    const float* bp = (const float*)d_in[8];

    const size_t N = (size_t)BH * T_ * DH;
    __bf16* qws  = (__bf16*)d_ws;
    __bf16* kws  = qws + N;
    __bf16* vtws = kws + N;
    __bf16* ows  = vtws + N;
    __bf16* wpb  = qws;                 // q dead after attn; 2 MiB needed

    qkv_kernel<<<dim3(16, 64), 256, 0, stream>>>(
        x, Wq, bq, Wk, bk, Wv, bv, qws, kws, vtws);
    attn_kernel<<<dim3(64, 16), 256, 0, stream>>>(qws, kws, vtws, ows);
    wpconv_kernel<<<dim3(1024), 256, 0, stream>>>(Wp, wpb);
    proj_kernel<<<dim3(64, 8), 256, 0, stream>>>(ows, wpb, bp, (float*)d_out);
}

// Round 14
// 211.184 us; speedup vs baseline: 1.0930x; 1.0135x over previous
//
#include <hip/hip_runtime.h>
#include <hip/hip_bf16.h>
#include <cstddef>

// Problem constants (SelfAttention: B=4, T=2048, H=16, Dh=64, C=1024)
#define B_  4
#define T_  2048
#define H_  16
#define DH  64
#define C_  1024
#define BH  64    // B_*H_

typedef float  f32x16 __attribute__((ext_vector_type(16)));
typedef __bf16 bf16x8 __attribute__((ext_vector_type(8)));
typedef __bf16 bf16x4 __attribute__((ext_vector_type(4)));

#define MFMA32(a, b, c) __builtin_amdgcn_mfma_f32_32x32x16_bf16(a, b, c, 0, 0, 0)

// mfma_f32_32x32x16_bf16 layouts (cdna4_isa / m74,m101 verified C/D):
//   A[m][k]: m = lane&31, k = (lane>>5)*8 + j   (8 bf16 per lane, b128)
//   B[k][n]: n = lane&31, k = (lane>>5)*8 + j
//   C/D:     col = lane&31, row = (reg&3) + 8*(reg>>2) + 4*(lane>>5)
//
// K/V are stored FRAGMENT-MAJOR in global:
//   Kf[bh][kt64][rh][ks][lane][8]  (elem = K[kt64*64+rh*32+(lane&31)][ks*16+(lane>>5)*8+j])
//   Vf[bh][kt64][dh][c ][lane][8]  (elem = V^T[dh*32+(lane&31)][kt64*64+c*16+(lane>>5)*8+j])
// so an attention fragment load is base + lane*16B: ONE coalesced 1KB
// transaction.
//
// Session ledger: R13 (this file minus proj-dbuf) measured 214.0 us total
// (attn 90.5 / tail 123.5) -- the session optimum. The only change here is
// proj double-buffering in its canonical form (stage immediately into the
// other buffer after ONE barrier/cb; nothing held in registers across the
// MFMA block -- unlike R6's regressing variant).

__device__ __forceinline__ unsigned cvt_pk_bf16(float lo, float hi) {
    unsigned r;
    asm("v_cvt_pk_bf16_f32 %0, %1, %2" : "=v"(r) : "v"(lo), "v"(hi));
    return r;
}

// ---------------------------------------------------------------------------
// Kernel 1: QKV projection, bf16 MFMA (R13 verbatim).
// ---------------------------------------------------------------------------
__global__ __launch_bounds__(256) void qkv_kernel(
    const float* __restrict__ x,
    const float* __restrict__ Wq, const float* __restrict__ bq,
    const float* __restrict__ Wk, const float* __restrict__ bk,
    const float* __restrict__ Wv, const float* __restrict__ bv,
    __bf16* __restrict__ q, __bf16* __restrict__ kf, __bf16* __restrict__ vf)
{
    __shared__ __bf16 Xs[128 * 72];          // x tile [t_local][d], bf16
    __shared__ __bf16 Ws[3][64 * 72];        // W[e][d], bf16
    __bf16* Vtl = Xs;                         // alias: V^T [e][t_local], stride 136
    __bf16* Kst = &Ws[0][0];                  // alias after mat loop: K [t_local][d], stride 72

    const int tt  = blockIdx.x;               // 0..15 (128-token tile)
    const int bh  = blockIdx.y;               // 0..63
    const int b   = bh >> 4, h = bh & 15;
    const int t0  = tt * 128;
    const int tid = threadIdx.x;
    const int wave = tid >> 6, lane = tid & 63;
    const int m = lane & 31, hh = lane >> 5;

    // stage x (fp32 -> bf16): 128 rows x 64 cols = 2048 float4 chunks
    #pragma unroll
    for (int i = 0; i < 8; ++i) {
        const int idx = i * 256 + tid;
        const int r = idx >> 4, c = (idx & 15) * 4;
        const float4 x4 = *(const float4*)(x + ((size_t)(b * T_ + t0 + r)) * C_ + h * DH + c);
        const unsigned lo = ((unsigned)__builtin_bit_cast(unsigned short, (__bf16)x4.y) << 16)
                          | (unsigned)__builtin_bit_cast(unsigned short, (__bf16)x4.x);
        const unsigned hi = ((unsigned)__builtin_bit_cast(unsigned short, (__bf16)x4.w) << 16)
                          | (unsigned)__builtin_bit_cast(unsigned short, (__bf16)x4.z);
        *(unsigned*)&Xs[r * 72 + c]     = lo;
        *(unsigned*)&Xs[r * 72 + c + 2] = hi;
    }
    // stage weights (fp32 -> bf16): 3 x 1024 float4 chunks
    #pragma unroll
    for (int i = 0; i < 4; ++i) {
        const int idx = i * 256 + tid;
        const int r = idx >> 4, c = (idx & 15) * 4;
        const float* wsrc[3] = {Wq, Wk, Wv};
        #pragma unroll
        for (int wv_ = 0; wv_ < 3; ++wv_) {
            const float4 w4 = *(const float4*)(wsrc[wv_] + r * 64 + c);
            const unsigned lo = ((unsigned)__builtin_bit_cast(unsigned short, (__bf16)w4.y) << 16)
                              | (unsigned)__builtin_bit_cast(unsigned short, (__bf16)w4.x);
            const unsigned hi = ((unsigned)__builtin_bit_cast(unsigned short, (__bf16)w4.w) << 16)
                              | (unsigned)__builtin_bit_cast(unsigned short, (__bf16)w4.z);
            *(unsigned*)&Ws[wv_][r * 72 + c]     = lo;
            *(unsigned*)&Ws[wv_][r * 72 + c + 2] = hi;
        }
    }
    __syncthreads();

    // hoist x A-fragments (wave-private rows 32*wave + m)
    bf16x8 xf[4];
    #pragma unroll
    for (int ks = 0; ks < 4; ++ks)
        xf[ks] = *(const bf16x8*)&Xs[(wave * 32 + m) * 72 + ks * 16 + hh * 8];
    __syncthreads();   // all frag reads done before Vtl aliases Xs

    // 1/sqrt(1024) * log2(e) folded into q (attention uses exp2 directly)
    const float s32 = 0.03125f * 1.4426950408889634f;

    unsigned kpk[16];   // packed k results, staged to LDS after the mat loop

    #pragma unroll
    for (int mat = 0; mat < 3; ++mat) {
        f32x16 acc0 = {}, acc1 = {};
        #pragma unroll
        for (int ks = 0; ks < 4; ++ks) {
            const bf16x8 w0 = *(const bf16x8*)&Ws[mat][(m) * 72 + ks * 16 + hh * 8];
            const bf16x8 w1 = *(const bf16x8*)&Ws[mat][(32 + m) * 72 + ks * 16 + hh * 8];
            acc0 = MFMA32(xf[ks], w0, acc0);
            acc1 = MFMA32(xf[ks], w1, acc1);
        }
        const float* bias = (mat == 0) ? bq : (mat == 1) ? bk : bv;
        const float b0 = bias[m], b1 = bias[32 + m];
        #pragma unroll
        for (int r = 0; r < 16; ++r) {
            const int R = (r & 3) + 8 * (r >> 2) + 4 * hh;   // token row in tile
            const int tloc = wave * 32 + R;
            const float v0 = acc0[r] + b0, v1 = acc1[r] + b1;
            if (mat == 0) {
                const size_t base = ((size_t)bh * T_ + t0 + tloc) * DH;
                q[base + m]      = (__bf16)(v0 * s32);
                q[base + 32 + m] = (__bf16)(v1 * s32);
            } else if (mat == 1) {
                kpk[r] = ((unsigned)__builtin_bit_cast(unsigned short, (__bf16)v1) << 16)
                       |  (unsigned)__builtin_bit_cast(unsigned short, (__bf16)v0);
            } else {
                Vtl[(m) * 136 + tloc]      = (__bf16)v0;   // V^T [e][t_local]
                Vtl[(32 + m) * 136 + tloc] = (__bf16)v1;
            }
        }
    }
    __syncthreads();   // Ws reads done (mat loop), Vtl complete

    // stage k tile [t_local][d] into Kst (Ws area, now dead)
    #pragma unroll
    for (int r = 0; r < 16; ++r) {
        const int R = (r & 3) + 8 * (r >> 2) + 4 * hh;
        const int tloc = wave * 32 + R;
        Kst[tloc * 72 + m]      = __builtin_bit_cast(__bf16, (unsigned short)(kpk[r] & 0xffff));
        Kst[tloc * 72 + 32 + m] = __builtin_bit_cast(__bf16, (unsigned short)(kpk[r] >> 16));
    }

    // Vf fragment-major out (reads Vtl; no barrier needed vs Kst region)
    #pragma unroll
    for (int i = 0; i < 4; ++i) {
        const int idx = i * 256 + tid;
        const int ln = idx & 63, c_ = idx >> 6;           // c_ 0..15
        const int kt64l = c_ >> 3, dh = (c_ >> 2) & 1, cN = c_ & 3;
        const __bf16* src = &Vtl[(dh * 32 + (ln & 31)) * 136 + kt64l * 64 + cN * 16 + (ln >> 5) * 8];
        __bf16* dst = vf + ((((size_t)(bh * 32 + tt * 2 + kt64l) * 2 + dh) * 4 + cN) * 64 + ln) * 8;
        *(uint4*)dst = *(const uint4*)src;
    }
    __syncthreads();   // Kst visible

    // Kf fragment-major out (reads Kst)
    #pragma unroll
    for (int i = 0; i < 4; ++i) {
        const int idx = i * 256 + tid;
        const int ln = idx & 63, c_ = idx >> 6;
        const int kt64l = c_ >> 3, rh = (c_ >> 2) & 1, ks = c_ & 3;
        const __bf16* src = &Kst[(kt64l * 64 + rh * 32 + (ln & 31)) * 72 + ks * 16 + (ln >> 5) * 8];
        __bf16* dst = kf + ((((size_t)(bh * 32 + tt * 2 + kt64l) * 2 + rh) * 4 + ks) * 64 + ln) * 8;
        *(uint4*)dst = *(const uint4*)src;
    }
}

// ---------------------------------------------------------------------------
// Kernel 2: flash attention (R13 verbatim -- the 90.5 us control).
// ---------------------------------------------------------------------------
__global__ __launch_bounds__(256, 4) void attn_kernel(
    const __bf16* __restrict__ q, const __bf16* __restrict__ kf,
    const __bf16* __restrict__ vf, __bf16* __restrict__ o)
{
    __shared__ __bf16 Os[128 * 72];          // epilogue transpose buffer

    const int bh  = blockIdx.x;              // XCD-locality axis (id%8 == bh%8)
    const int q0  = blockIdx.y * 128;
    const int tid = threadIdx.x;
    const int wave = tid >> 6, lane = tid & 63;
    const int m = lane & 31, h = lane >> 5;

    const __bf16* qb  = q  + (size_t)bh * T_ * DH;
    const __bf16* kfb = kf + (size_t)bh * (T_ * DH);   // [kt64][rh][ks][lane][8]
    const __bf16* vfb = vf + (size_t)bh * (T_ * DH);   // [kt64][dh][c ][lane][8]

    // Q fragments (one-time; [t][d] layout, segmented but negligible)
    bf16x8 qf[4];
    #pragma unroll
    for (int ks = 0; ks < 4; ++ks)
        qf[ks] = *(const bf16x8*)(qb + (size_t)(q0 + wave * 32 + m) * DH + ks * 16 + h * 8);

    f32x16 O0 = {}, O1 = {};                 // O^T [d 0..31 | 32..63][q]
    float lsum = 0.f;

    for (int kt = 0; kt < 32; ++kt) {
        const __bf16* kt_k = kfb + kt * 4096;
        const __bf16* kt_v = vfb + kt * 4096;
        #pragma unroll
        for (int rh = 0; rh < 2; ++rh) {
            bf16x8 kfr[4];
            #pragma unroll
            for (int ks = 0; ks < 4; ++ks)
                kfr[ks] = *(const bf16x8*)(kt_k + rh * 2048 + ks * 512 + lane * 8);
            f32x16 S = {};
            #pragma unroll
            for (int ks = 0; ks < 4; ++ks)
                S = MFMA32(kfr[ks], qf[ks], S);

            #pragma unroll
            for (int cc = 0; cc < 2; ++cc) {
                const int rb = cc * 8;
                float e0 = __builtin_amdgcn_exp2f(S[rb + 0]);
                float e1 = __builtin_amdgcn_exp2f(S[rb + 1]);
                float e2 = __builtin_amdgcn_exp2f(S[rb + 2]);
                float e3 = __builtin_amdgcn_exp2f(S[rb + 3]);
                float e4 = __builtin_amdgcn_exp2f(S[rb + 4]);
                float e5 = __builtin_amdgcn_exp2f(S[rb + 5]);
                float e6 = __builtin_amdgcn_exp2f(S[rb + 6]);
                float e7 = __builtin_amdgcn_exp2f(S[rb + 7]);
                lsum += ((e0 + e1) + (e2 + e3)) + ((e4 + e5) + (e6 + e7));
                unsigned a0 = cvt_pk_bf16(e0, e1);
                unsigned a1 = cvt_pk_bf16(e2, e3);
                unsigned b0 = cvt_pk_bf16(e4, e5);
                unsigned b1 = cvt_pk_bf16(e6, e7);
                asm("v_permlane32_swap_b32 %0, %1" : "+v"(a0), "+v"(b0));
                asm("v_permlane32_swap_b32 %0, %1" : "+v"(a1), "+v"(b1));
                const uint4 pw = {a0, a1, b0, b1};
                const bf16x8 pb = __builtin_bit_cast(bf16x8, pw);
                const int c = rh * 2 + cc;          // kv 16-slot
                const bf16x8 v0 = *(const bf16x8*)(kt_v + c * 512 + lane * 8);
                const bf16x8 v1 = *(const bf16x8*)(kt_v + 2048 + c * 512 + lane * 8);
                O0 = MFMA32(v0, pb, O0);
                O1 = MFMA32(v1, pb, O1);
            }
        }
    }

    // l[q]: lanes l and l+32 hold complementary kv halves of the same q-row
    lsum += __shfl_xor(lsum, 32);
    const float linv = 1.0f / lsum;

    // O^T -> LDS: lane owns q-row (wave*32 + m); reg r -> d = (r&3)+8*(r>>2)+4h
    #pragma unroll
    for (int g = 0; g < 4; ++g) {
        bf16x4 w0, w1;
        #pragma unroll
        for (int j = 0; j < 4; ++j) {
            w0[j] = (__bf16)(O0[4 * g + j] * linv);
            w1[j] = (__bf16)(O1[4 * g + j] * linv);
        }
        const int row = (wave * 32 + m) * 72;
        *(bf16x4*)&Os[row + 8 * g + 4 * h]      = w0;
        *(bf16x4*)&Os[row + 32 + 8 * g + 4 * h] = w1;
    }
    __syncthreads();

    // fully coalesced store: 128 rows x 64 bf16 = 1024 uint4 / 256 threads
    __bf16* ob = o + ((size_t)bh * T_ + q0) * DH;
    #pragma unroll
    for (int i = 0; i < 4; ++i) {
        const int idx = i * 256 + tid;
        const int r = idx >> 3, c = (idx & 7) * 8;
        *(uint4*)(ob + (size_t)r * DH + c) = *(uint4*)&Os[r * 72 + c];
    }
}

// ---------------------------------------------------------------------------
// Kernel 2.5: Wp fp32 -> bf16 pre-conversion (once; into dead q region).
// ---------------------------------------------------------------------------
__global__ __launch_bounds__(256) void wpconv_kernel(
    const float* __restrict__ Wp, __bf16* __restrict__ Wpb)
{
    const size_t idx = (size_t)(blockIdx.x * 256 + threadIdx.x) * 4;
    const float4 w4 = *(const float4*)(Wp + idx);
    const unsigned lo = ((unsigned)__builtin_bit_cast(unsigned short, (__bf16)w4.y) << 16)
                      | (unsigned)__builtin_bit_cast(unsigned short, (__bf16)w4.x);
    const unsigned hi = ((unsigned)__builtin_bit_cast(unsigned short, (__bf16)w4.w) << 16)
                      | (unsigned)__builtin_bit_cast(unsigned short, (__bf16)w4.z);
    uint2 p; p.x = lo; p.y = hi;
    *(uint2*)(Wpb + idx) = p;
}

// ---------------------------------------------------------------------------
// Kernel 3: output projection, bf16 MFMA, DOUBLE-BUFFERED LDS (canonical
// form): one barrier per cb; stage(cb+1) goes into the other buffer right
// after the barrier (nothing held in registers across the MFMA block).
// Barrier count 32 -> 16; stage latency of cb+1 overlaps MFMA of cb across
// the 8 resident waves. LDS 73.7 KB -> 2 blocks/CU (unchanged occupancy).
// ---------------------------------------------------------------------------
__global__ __launch_bounds__(256) void proj_kernel(
    const __bf16* __restrict__ a,      // [bh][t][d]
    const __bf16* __restrict__ Wpb, const float* __restrict__ bp,
    float* __restrict__ out)
{
    __shared__ __bf16 As[2][128 * 72];
    __shared__ __bf16 Bs[2][128 * 72];

    const int tb = blockIdx.x, eb = blockIdx.y;
    const int tid = threadIdx.x;
    const int wave = tid >> 6, lane = tid & 63;
    const int m = lane & 31, h = lane >> 5;
    const int tok0 = tb * 128;
    const int b = tok0 >> 11, t0 = tok0 & (T_ - 1);
    const int e0 = eb * 128;

    auto stage = [&](int buf, int cb) {
        #pragma unroll
        for (int i = 0; i < 4; ++i) {
            const int idx = i * 256 + tid;
            const int r = idx >> 3, c = (idx & 7) * 8;
            *(uint4*)&As[buf][r * 72 + c] =
                *(const uint4*)(a + ((size_t)(b * H_ + cb) * T_ + t0 + r) * DH + c);
            *(uint4*)&Bs[buf][r * 72 + c] =
                *(const uint4*)(Wpb + (size_t)(e0 + r) * C_ + cb * 64 + c);
        }
    };

    f32x16 acc[4] = {f32x16{}, f32x16{}, f32x16{}, f32x16{}};

    stage(0, 0);
    int cur = 0;
    for (int cb = 0; cb < 16; ++cb) {
        __syncthreads();               // buf[cur] staged; buf[cur^1] reads done
        if (cb < 15) stage(cur ^ 1, cb + 1);

        #pragma unroll
        for (int ks = 0; ks < 4; ++ks) {
            const bf16x8 af = *(const bf16x8*)&As[cur][(wave * 32 + m) * 72 + ks * 16 + h * 8];
            #pragma unroll
            for (int n = 0; n < 4; ++n) {
                const bf16x8 bf = *(const bf16x8*)&Bs[cur][(n * 32 + m) * 72 + ks * 16 + h * 8];
                acc[n] = MFMA32(af, bf, acc[n]);
            }
        }
        cur ^= 1;
    }

    #pragma unroll
    for (int n = 0; n < 4; ++n) {
        const int e = e0 + n * 32 + m;
        const float bias = bp[e];
        #pragma unroll
        for (int r = 0; r < 16; ++r) {
            const int R = (r & 3) + 8 * (r >> 2) + 4 * h;
            out[(size_t)(tok0 + wave * 32 + R) * C_ + e] = acc[n][r] + bias;
        }
    }
}

// ---------------------------------------------------------------------------
// Workspace (bf16): q | kf | vf | attn_out, each B*H*T*DH = 8388608 elems
// -> 64 MiB total. Wpb (2 MiB) reuses the q region (dead after attn).
// ---------------------------------------------------------------------------
extern "C" void kernel_launch(void* const* d_in, const int* in_sizes, int n_in,
                              void* d_out, int out_size, void* d_ws, size_t ws_size,
                              hipStream_t stream)
{
    const float* x  = (const float*)d_in[0];
    const float* Wq = (const float*)d_in[1];
    const float* bq = (const float*)d_in[2];
    const float* Wk = (const float*)d_in[3];
    const float* bk = (const float*)d_in[4];
    const float* Wv = (const float*)d_in[5];
    const float* bv = (const float*)d_in[6];
    const float* Wp = (const float*)d_in[7];
    const float* bp = (const float*)d_in[8];

    const size_t N = (size_t)BH * T_ * DH;
    __bf16* qws  = (__bf16*)d_ws;
    __bf16* kws  = qws + N;
    __bf16* vtws = kws + N;
    __bf16* ows  = vtws + N;
    __bf16* wpb  = qws;                 // q dead after attn; 2 MiB needed

    qkv_kernel<<<dim3(16, 64), 256, 0, stream>>>(
        x, Wq, bq, Wk, bk, Wv, bv, qws, kws, vtws);
    attn_kernel<<<dim3(64, 16), 256, 0, stream>>>(qws, kws, vtws, ows);
    wpconv_kernel<<<dim3(1024), 256, 0, stream>>>(Wp, wpb);
    proj_kernel<<<dim3(64, 8), 256, 0, stream>>>(ows, wpb, bp, (float*)d_out);
}